// Round 1
// baseline (290.475 us; speedup 1.0000x reference)
//
#include <hip/hip_runtime.h>

#define BB 16
#define NQn 8
#define NK 4096
#define CC 256
#define NHEADS 8
#define CIn 128
#define HDn 16
#define NHQ 64
#define EPS_TINY 1.17549435e-38f

// workspace float offsets
constexpr size_t OFF_QK   = 0;                                   // B*C*NHQ
constexpr size_t OFF_QBK  = OFF_QK  + (size_t)BB*CC*NHQ;         // B*NHQ
constexpr size_t OFF_SC   = OFF_QBK + (size_t)BB*NHQ;            // B*NK*NHQ
constexpr size_t OFF_MP   = OFF_SC  + (size_t)BB*NK*NHQ;         // B*16*NHQ
constexpr size_t OFF_SP   = OFF_MP  + (size_t)BB*16*NHQ;
constexpr size_t OFF_M    = OFF_SP  + (size_t)BB*16*NHQ;         // B*NHQ
constexpr size_t OFF_RS   = OFF_M   + (size_t)BB*NHQ;
constexpr size_t OFF_AVP  = OFF_RS  + (size_t)BB*NHQ;            // B*16*NHQ*C
constexpr size_t OFF_QATT = OFF_AVP + (size_t)BB*16*NHQ*CC;      // B*NQ*C
constexpr size_t OFF_UNC  = OFF_QATT+ (size_t)BB*NQn*CC;         // B*C
constexpr size_t OFF_REFT = OFF_UNC + (size_t)BB*CC;             // B*C
constexpr size_t OFF_RMAP = OFF_REFT+ (size_t)BB*CC;             // B*NK
constexpr size_t OFF_IDX  = OFF_RMAP+ (size_t)BB*NK;             // 128 ints
constexpr size_t OFF_RV   = OFF_IDX + 128;                       // 128 floats

// K1: qh = (queries+query_pe)@Wq+bq (scaled by 1/4); fold Wk,bk into query side:
// Qk[b][c][hq] = sum_d qh[d]*Wk[c, h*16+d],  qbk[b][hq] = sum_d qh[d]*bk[h*16+d]
__global__ __launch_bounds__(256) void k1_qside(
    const float* __restrict__ queries, const float* __restrict__ query_pe,
    const float* __restrict__ Wq, const float* __restrict__ bq,
    const float* __restrict__ Wk, const float* __restrict__ bk,
    float* __restrict__ ws)
{
  int b = blockIdx.x >> 3, q = blockIdx.x & 7, t = threadIdx.x;
  __shared__ float x[CC];
  __shared__ float qh[CIn];
  x[t] = queries[(b*NQn+q)*CC + t] + query_pe[(b*NQn+q)*CC + t];
  __syncthreads();
  if (t < CIn) {
    float a = bq[t];
    for (int c = 0; c < CC; ++c) a += x[c]*Wq[c*CIn + t];
    qh[t] = a * 0.25f;   // fold 1/sqrt(HD)=1/4 into query side
  }
  __syncthreads();
  float* Qk = ws + OFF_QK;
  #pragma unroll
  for (int h = 0; h < NHEADS; ++h) {
    float a = 0.f;
    #pragma unroll
    for (int d = 0; d < HDn; ++d) a += qh[h*HDn+d] * Wk[t*CIn + h*HDn + d];
    Qk[((size_t)b*CC + t)*NHQ + h*NQn + q] = a;
  }
  if (t < NHEADS) {
    float a = 0.f;
    #pragma unroll
    for (int d = 0; d < HDn; ++d) a += qh[t*HDn+d] * bk[t*HDn+d];
    (ws + OFF_QBK)[b*NHQ + t*NQn + q] = a;
  }
}

// K2: scores[b][k][hq] = sum_c (g+key_pe)[k,c] * Qk[c][hq] + qbk[hq],  g=keys*guiding
// 64 k-rows per block, 64 hq, K=256 in chunks of 64; 16x16 thread tile (4k x 4hq each).
__global__ __launch_bounds__(256) void k2_scores(
    const float* __restrict__ keys, const float* __restrict__ key_pe,
    const float* __restrict__ guiding, float* __restrict__ ws)
{
  int b = blockIdx.y, n0 = blockIdx.x * 64, t = threadIdx.x;
  __shared__ __align__(16) float Xt[64][68];   // [c_local][k], pad 68 (272B rows, 16B aligned)
  __shared__ __align__(16) float Qs[64][64];   // [c_local][hq]
  const float* Qk = ws + OFF_QK;
  int lane = t & 63, grp = t >> 6;
  int tx = t & 15, ty = t >> 4;
  float acc[4][4] = {};
  for (int c0 = 0; c0 < CC; c0 += 64) {
    __syncthreads();
    #pragma unroll 4
    for (int cc = 0; cc < 16; ++cc) {
      int c = c0 + grp*16 + cc;
      float kv = keys[((size_t)b*NK + n0 + lane)*CC + c];
      float gv = guiding[((size_t)b*CC + c)*NK + n0 + lane];
      float pv = key_pe[((size_t)b*NK + n0 + lane)*CC + c];
      Xt[grp*16+cc][lane] = kv*gv + pv;
    }
    #pragma unroll 4
    for (int i = 0; i < 16; ++i) {
      int l = i*256 + t;
      Qs[l >> 6][l & 63] = Qk[((size_t)b*CC + c0 + (l>>6))*NHQ + (l & 63)];
    }
    __syncthreads();
    #pragma unroll 4
    for (int c = 0; c < 64; ++c) {
      float4 xv = *(const float4*)&Xt[c][4*ty];
      float4 qv = *(const float4*)&Qs[c][4*tx];
      float xs4[4] = {xv.x, xv.y, xv.z, xv.w};
      float qs4[4] = {qv.x, qv.y, qv.z, qv.w};
      #pragma unroll
      for (int i = 0; i < 4; ++i)
        #pragma unroll
        for (int j = 0; j < 4; ++j) acc[i][j] += xs4[i]*qs4[j];
    }
  }
  const float* qbk = ws + OFF_QBK + (size_t)b*NHQ;
  float qb[4] = {qbk[4*tx], qbk[4*tx+1], qbk[4*tx+2], qbk[4*tx+3]};
  float* sc = ws + OFF_SC + ((size_t)b*NK + n0)*NHQ;
  #pragma unroll
  for (int i = 0; i < 4; ++i) {
    float4 o;
    o.x = acc[i][0]+qb[0]; o.y = acc[i][1]+qb[1]; o.z = acc[i][2]+qb[2]; o.w = acc[i][3]+qb[3];
    *(float4*)&sc[(4*ty + i)*NHQ + 4*tx] = o;
  }
}

// K3a: per-(b, 256-k subblock) online (max, sumexp) partials per hq
__global__ __launch_bounds__(256) void k3a_stats(float* __restrict__ ws)
{
  int b = blockIdx.y, sb = blockIdx.x, t = threadIdx.x;
  int hq = t & 63, r = t >> 6;
  const float* sc = ws + OFF_SC + ((size_t)b*NK + sb*256)*NHQ;
  float m = -INFINITY, s = 0.f;
  for (int i = 0; i < 64; ++i) {
    float v = sc[(r + 4*i)*NHQ + hq];
    if (v > m) { s = s*expf(m - v) + 1.f; m = v; } else { s += expf(v - m); }
  }
  __shared__ float rm[256], rs[256];
  rm[t] = m; rs[t] = s;
  __syncthreads();
  if (t < 64) {
    float m0=rm[t], m1=rm[t+64], m2=rm[t+128], m3=rm[t+192];
    float mm = fmaxf(fmaxf(m0,m1), fmaxf(m2,m3));
    float ss = rs[t]*expf(m0-mm) + rs[t+64]*expf(m1-mm) + rs[t+128]*expf(m2-mm) + rs[t+192]*expf(m3-mm);
    (ws + OFF_MP)[(b*16 + sb)*NHQ + t] = mm;
    (ws + OFF_SP)[(b*16 + sb)*NHQ + t] = ss;
  }
}

// K3b: combine 16 partials -> m, 1/s per (b,hq)
__global__ __launch_bounds__(64) void k3b_combine(float* __restrict__ ws)
{
  int b = blockIdx.x, hq = threadIdx.x;
  const float* mp = ws + OFF_MP + (size_t)b*16*NHQ;
  const float* sp = ws + OFF_SP + (size_t)b*16*NHQ;
  float m = -INFINITY;
  #pragma unroll
  for (int i = 0; i < 16; ++i) m = fmaxf(m, mp[i*NHQ+hq]);
  float s = 0.f;
  #pragma unroll
  for (int i = 0; i < 16; ++i) s += sp[i*NHQ+hq]*expf(mp[i*NHQ+hq]-m);
  (ws+OFF_M)[b*NHQ+hq] = m;
  (ws+OFF_RS)[b*NHQ+hq] = 1.0f/s;
}

// K4: AVpart[b][kb][hq][c] = sum_{k in kb} attn[k,hq]*g[k,c]; 256 k per block, chunks of 32
__global__ __launch_bounds__(256) void k4_av(
    const float* __restrict__ keys, const float* __restrict__ guiding,
    float* __restrict__ ws)
{
  int b = blockIdx.y, kb = blockIdx.x, t = threadIdx.x;
  int k0 = kb * 256;
  __shared__ __align__(16) float gld[32][260];  // [k][c], pad 260 (1040B rows, 16B aligned)
  __shared__ __align__(16) float wld[32][64];
  __shared__ float mv[64], rv[64];
  if (t < 64) { mv[t] = (ws+OFF_M)[b*NHQ+t]; rv[t] = (ws+OFF_RS)[b*NHQ+t]; }
  int th = t & 15, tc = t >> 4;
  float accf[4][16] = {};
  const float* sc = ws + OFF_SC;
  for (int kk = 0; kk < 256; kk += 32) {
    __syncthreads();
    #pragma unroll 4
    for (int k = 0; k < 32; ++k) {
      float kv = keys[((size_t)b*NK + k0+kk+k)*CC + t];
      float gv = guiding[((size_t)b*CC + t)*NK + k0+kk+k];
      gld[k][t] = kv*gv;
    }
    #pragma unroll
    for (int i = 0; i < 8; ++i) {
      int l = i*256 + t; int k = l >> 6, hq = l & 63;
      float v = sc[((size_t)b*NK + k0+kk+k)*NHQ + hq];
      wld[k][hq] = expf(v - mv[hq]) * rv[hq];
    }
    __syncthreads();
    for (int k = 0; k < 32; ++k) {
      float4 w4 = *(const float4*)&wld[k][4*th];
      float4 g0 = *(const float4*)&gld[k][16*tc];
      float4 g1 = *(const float4*)&gld[k][16*tc+4];
      float4 g2 = *(const float4*)&gld[k][16*tc+8];
      float4 g3 = *(const float4*)&gld[k][16*tc+12];
      float wq[4] = {w4.x, w4.y, w4.z, w4.w};
      float gq[16] = {g0.x,g0.y,g0.z,g0.w, g1.x,g1.y,g1.z,g1.w,
                      g2.x,g2.y,g2.z,g2.w, g3.x,g3.y,g3.z,g3.w};
      #pragma unroll
      for (int i = 0; i < 4; ++i)
        #pragma unroll
        for (int j = 0; j < 16; ++j) accf[i][j] += wq[i]*gq[j];
    }
  }
  float* avp = ws + OFF_AVP + (((size_t)b*16 + kb)*NHQ)*CC;
  #pragma unroll
  for (int i = 0; i < 4; ++i)
    #pragma unroll
    for (int j4 = 0; j4 < 4; ++j4) {
      float4 o;
      o.x = accf[i][4*j4]; o.y = accf[i][4*j4+1]; o.z = accf[i][4*j4+2]; o.w = accf[i][4*j4+3];
      *(float4*)&avp[(4*th + i)*CC + 16*tc + 4*j4] = o;
    }
}

// K56: reduce AVpart, then out = AV@Wv+bv (per head), queries_att = out@Wo+bo
__global__ __launch_bounds__(256) void k56_attout(
    const float* __restrict__ Wv, const float* __restrict__ bv,
    const float* __restrict__ Wo, const float* __restrict__ bo,
    float* __restrict__ ws)
{
  int b = blockIdx.x >> 3, q = blockIdx.x & 7, t = threadIdx.x;
  __shared__ float avs[NHEADS][CC];
  __shared__ float outv[CIn];
  const float* avp = ws + OFF_AVP;
  #pragma unroll
  for (int h = 0; h < NHEADS; ++h) {
    int hq = h*NQn + q;
    float a = 0.f;
    #pragma unroll 4
    for (int kb = 0; kb < 16; ++kb)
      a += avp[(((size_t)b*16 + kb)*NHQ + hq)*CC + t];
    avs[h][t] = a;
  }
  __syncthreads();
  if (t < CIn) {
    int h = t >> 4;
    float a = bv[t];
    for (int c = 0; c < CC; ++c) a += avs[h][c]*Wv[c*CIn + t];
    outv[t] = a;
  }
  __syncthreads();
  float a = bo[t];
  for (int ci = 0; ci < CIn; ++ci) a += outv[ci]*Wo[ci*CC + t];
  (ws+OFF_QATT)[((size_t)b*NQn + q)*CC + t] = a;
}

// K7: the two 3-layer MLPs on concat(static, q1)
__global__ __launch_bounds__(256) void k7_mlps(
    const float* __restrict__ su, const float* __restrict__ sr,
    const float* __restrict__ uW1, const float* __restrict__ ub1,
    const float* __restrict__ uW2, const float* __restrict__ ub2,
    const float* __restrict__ uW3, const float* __restrict__ ub3,
    const float* __restrict__ rW1, const float* __restrict__ rb1,
    const float* __restrict__ rW2, const float* __restrict__ rb2,
    const float* __restrict__ rW3, const float* __restrict__ rb3,
    float* __restrict__ ws)
{
  int b = blockIdx.x, t = threadIdx.x;
  __shared__ float xs[768];
  __shared__ float h1[2][64], h2[2][64];
  xs[t] = su[t];
  xs[256+t] = (ws+OFF_QATT)[((size_t)b*NQn + 1)*CC + t];
  xs[512+t] = sr[t];
  __syncthreads();
  if (t < 128) {
    int which = t >> 6, o = t & 63;
    const float* W1 = which ? rW1 : uW1;
    const float* b1 = which ? rb1 : ub1;
    int base = which ? 512 : 0;
    float a = b1[o];
    for (int i = 0; i < 256; ++i) a += xs[base+i]*W1[i*64 + o];
    for (int i = 0; i < 256; ++i) a += xs[256+i]*W1[(256+i)*64 + o];
    h1[which][o] = fmaxf(a, 0.f);
  }
  __syncthreads();
  if (t < 128) {
    int which = t >> 6, o = t & 63;
    const float* W2 = which ? rW2 : uW2;
    const float* b2 = which ? rb2 : ub2;
    float a = b2[o];
    #pragma unroll 8
    for (int i = 0; i < 64; ++i) a += h1[which][i]*W2[i*64+o];
    h2[which][o] = fmaxf(a, 0.f);
  }
  __syncthreads();
  {
    float a = ub3[t];
    #pragma unroll 8
    for (int i = 0; i < 64; ++i) a += h2[0][i]*uW3[i*CC + t];
    (ws+OFF_UNC)[b*CC + t] = a;
    float a2 = rb3[t];
    #pragma unroll 8
    for (int i = 0; i < 64; ++i) a2 += h2[1][i]*rW3[i*CC + t];
    (ws+OFF_REFT)[b*CC + t] = a2;
  }
}

// K8: three dots over c of g[b,n,:] with {q1, unc_tok, ref_tok}; ref_map
__global__ __launch_bounds__(256) void k8_masks(
    const float* __restrict__ keys, const float* __restrict__ guiding,
    float* __restrict__ ws)
{
  int b = blockIdx.y, n0 = blockIdx.x*256, t = threadIdx.x;
  __shared__ float q1s[CC], us[CC], rts[CC];
  q1s[t] = (ws+OFF_QATT)[((size_t)b*NQn+1)*CC + t];
  us[t]  = (ws+OFF_UNC)[b*CC + t];
  rts[t] = (ws+OFF_REFT)[b*CC + t];
  __syncthreads();
  float aq=0.f, au=0.f, ar=0.f;
  int n = n0 + t;
  for (int c = 0; c < CC; ++c) {
    float kv = keys[((size_t)b*NK + n)*CC + c];
    float gv = guiding[((size_t)b*CC + c)*NK + n];
    float g = kv*gv;
    aq += g*q1s[c]; au += g*us[c]; ar += g*rts[c];
  }
  float un = 1.f/(1.f+expf(-au));
  float rmap = un * (1.f/(1.f+expf(-ar)) - 1.f/(1.f+expf(-aq)));
  (ws+OFF_RMAP)[(size_t)b*NK + n] = rmap;
}

// K9: gumbel-softmax iterative top-4 (replicates reference numerics in fp32)
__global__ __launch_bounds__(256) void k9_gumbel(
    const float* __restrict__ gp, const float* __restrict__ gn,
    float* __restrict__ ws)
{
  int sign = blockIdx.x, b = blockIdx.y, t = threadIdx.x;
  const float* noise = sign ? gn : gp;
  const float* rmap = ws + OFF_RMAP + (size_t)b*NK;
  float g[16], kh[16], oh[16];
  #pragma unroll
  for (int i = 0; i < 16; ++i) {
    int n = i*256 + t;
    float scv = rmap[n];
    if (sign) scv = -scv;
    g[i] = scv + noise[(size_t)b*NK + n];
    kh[i] = 0.f; oh[i] = 0.f;
  }
  __shared__ float rv[256];
  __shared__ int ri[256];
  for (int it = 0; it < 4; ++it) {
    if (it > 0) {
      #pragma unroll
      for (int i = 0; i < 16; ++i) g[i] += logf(fmaxf(1.f - oh[i], EPS_TINY));
    }
    float m = g[0];
    #pragma unroll
    for (int i = 1; i < 16; ++i) m = fmaxf(m, g[i]);
    rv[t] = m; __syncthreads();
    for (int s = 128; s > 0; s >>= 1) { if (t < s) rv[t] = fmaxf(rv[t], rv[t+s]); __syncthreads(); }
    m = rv[0]; __syncthreads();
    float e[16], ls = 0.f;
    #pragma unroll
    for (int i = 0; i < 16; ++i) { e[i] = expf(g[i]-m); ls += e[i]; }
    rv[t] = ls; __syncthreads();
    for (int s = 128; s > 0; s >>= 1) { if (t < s) rv[t] += rv[t+s]; __syncthreads(); }
    float ssum = rv[0]; __syncthreads();
    #pragma unroll
    for (int i = 0; i < 16; ++i) { oh[i] = e[i]/ssum; kh[i] += oh[i]; }
  }
  __shared__ int selI[4]; __shared__ float selR[4];
  for (int j = 0; j < 4; ++j) {
    float bvv = kh[0]; int bii = t;
    #pragma unroll
    for (int i = 1; i < 16; ++i) {
      if (kh[i] > bvv) { bvv = kh[i]; bii = i*256 + t; }  // within-thread: increasing n, strict > keeps lowest
    }
    rv[t] = bvv; ri[t] = bii; __syncthreads();
    for (int s = 128; s > 0; s >>= 1) {
      if (t < s) {
        float v2 = rv[t+s]; int i2 = ri[t+s];
        if (v2 > rv[t] || (v2 == rv[t] && i2 < ri[t])) { rv[t] = v2; ri[t] = i2; }
      }
      __syncthreads();
    }
    int bidx = ri[0]; float bkh = rv[0];
    if (t == 0) { selI[j] = bidx; selR[j] = (1.f - bkh) + bkh; }
    if (t == (bidx & 255)) {
      int slot = bidx >> 8;
      #pragma unroll
      for (int i = 0; i < 16; ++i) if (i == slot) kh[i] = -1.f;  // exclude
    }
    __syncthreads();
  }
  if (t == 0) {
    int id[4]; float rr[4];
    #pragma unroll
    for (int j = 0; j < 4; ++j) { id[j] = selI[j]; rr[j] = selR[j]; }
    for (int a = 0; a < 3; ++a)
      for (int c2 = a+1; c2 < 4; ++c2)
        if (id[c2] < id[a]) { int ti=id[a]; id[a]=id[c2]; id[c2]=ti; float tr=rr[a]; rr[a]=rr[c2]; rr[c2]=tr; }
    int* iout = (int*)(ws + OFF_IDX);
    float* rout = ws + OFF_RV;
    for (int j = 0; j < 4; ++j) {
      iout[(sign*BB + b)*4 + j] = id[j];
      rout[(sign*BB + b)*4 + j] = rr[j];
    }
  }
}

// K10: assemble (b, 32, 256) output
__global__ __launch_bounds__(256) void k10_out(
    const float* __restrict__ keys, const float* __restrict__ guiding,
    const float* __restrict__ query_pe,
    const float* __restrict__ point_pos, const float* __restrict__ point_neg,
    const float* __restrict__ pe_gauss,
    float* __restrict__ ws, float* __restrict__ out)
{
  int b = blockIdx.y, r = blockIdx.x, t = threadIdx.x;
  float val;
  if (r < 8) {
    val = (r == 1) ? (ws+OFF_REFT)[b*CC + t]
                   : (ws+OFF_QATT)[((size_t)b*NQn + r)*CC + t];
  } else if (r < 16) {
    int j = r - 8; int sign = j >> 2; int jj = j & 3;
    int idx = ((const int*)(ws+OFF_IDX))[(sign*BB + b)*4 + jj];
    float rvv = (ws+OFF_RV)[(sign*BB + b)*4 + jj];
    float kv = keys[((size_t)b*NK + idx)*CC + t];
    float gv = guiding[((size_t)b*CC + t)*NK + idx];
    val = (kv + kv*gv) * rvv;
  } else if (r < 24) {
    val = query_pe[((size_t)b*NQn + (r-16))*CC + t];
  } else {
    int j = r - 24; int sign = j >> 2; int jj = j & 3;
    int idx = ((const int*)(ws+OFF_IDX))[(sign*BB + b)*4 + jj];
    float rvv = (ws+OFF_RV)[(sign*BB + b)*4 + jj];
    const float* point = sign ? point_neg : point_pos;
    int h = idx >> 6, w = idx & 63;
    float x = (w + 0.5f)/64.f, y = (h + 0.5f)/64.f;
    int jf = (t < 128) ? t : (t - 128);
    float proj = ((2.f*x - 1.f)*pe_gauss[jf] + (2.f*y - 1.f)*pe_gauss[128 + jf]) * 6.28318530717958647692f;
    float sv = (t < 128) ? sinf(proj) : cosf(proj);
    val = sv*rvv + point[t];
  }
  out[((size_t)b*32 + r)*CC + t] = val;
}

extern "C" void kernel_launch(void* const* d_in, const int* in_sizes, int n_in,
                              void* d_out, int out_size, void* d_ws, size_t ws_size,
                              hipStream_t stream)
{
  const float* queries   = (const float*)d_in[0];
  const float* keys      = (const float*)d_in[1];
  const float* query_pe  = (const float*)d_in[2];
  const float* key_pe    = (const float*)d_in[3];
  const float* guiding   = (const float*)d_in[4];
  const float* gumbel_p  = (const float*)d_in[5];
  const float* gumbel_n  = (const float*)d_in[6];
  const float* s_unc     = (const float*)d_in[7];
  const float* s_ref     = (const float*)d_in[8];
  const float* Wq  = (const float*)d_in[9];   const float* bq  = (const float*)d_in[10];
  const float* Wk  = (const float*)d_in[11];  const float* bk  = (const float*)d_in[12];
  const float* Wv  = (const float*)d_in[13];  const float* bv  = (const float*)d_in[14];
  const float* Wo  = (const float*)d_in[15];  const float* bo  = (const float*)d_in[16];
  const float* uW1 = (const float*)d_in[17];  const float* ub1 = (const float*)d_in[18];
  const float* uW2 = (const float*)d_in[19];  const float* ub2 = (const float*)d_in[20];
  const float* uW3 = (const float*)d_in[21];  const float* ub3 = (const float*)d_in[22];
  const float* rW1 = (const float*)d_in[23];  const float* rb1 = (const float*)d_in[24];
  const float* rW2 = (const float*)d_in[25];  const float* rb2 = (const float*)d_in[26];
  const float* rW3 = (const float*)d_in[27];  const float* rb3 = (const float*)d_in[28];
  const float* pe_gauss  = (const float*)d_in[29];
  const float* point_pos = (const float*)d_in[30];
  const float* point_neg = (const float*)d_in[31];
  float* ws = (float*)d_ws;
  float* out = (float*)d_out;

  k1_qside  <<<dim3(BB*NQn),  256, 0, stream>>>(queries, query_pe, Wq, bq, Wk, bk, ws);
  k2_scores <<<dim3(64, BB),  256, 0, stream>>>(keys, key_pe, guiding, ws);
  k3a_stats <<<dim3(16, BB),  256, 0, stream>>>(ws);
  k3b_combine<<<dim3(BB),      64, 0, stream>>>(ws);
  k4_av     <<<dim3(16, BB),  256, 0, stream>>>(keys, guiding, ws);
  k56_attout<<<dim3(BB*NQn),  256, 0, stream>>>(Wv, bv, Wo, bo, ws);
  k7_mlps   <<<dim3(BB),      256, 0, stream>>>(s_unc, s_ref, uW1, ub1, uW2, ub2, uW3, ub3,
                                                rW1, rb1, rW2, rb2, rW3, rb3, ws);
  k8_masks  <<<dim3(16, BB),  256, 0, stream>>>(keys, guiding, ws);
  k9_gumbel <<<dim3(2, BB),   256, 0, stream>>>(gumbel_p, gumbel_n, ws);
  k10_out   <<<dim3(32, BB),  256, 0, stream>>>(keys, guiding, query_pe, point_pos, point_neg,
                                                pe_gauss, ws, out);
}

// Round 2
// 254.743 us; speedup vs baseline: 1.1403x; 1.1403x over previous
//
#include <hip/hip_runtime.h>

#define BB 16
#define NQn 8
#define NK 4096
#define CC 256
#define NHEADS 8
#define CIn 128
#define HDn 16
#define NHQ 64
#define EPS_TINY 1.17549435e-38f

// workspace float offsets
constexpr size_t OFF_QK   = 0;                                   // B*C*NHQ
constexpr size_t OFF_QBK  = OFF_QK  + (size_t)BB*CC*NHQ;         // B*NHQ
constexpr size_t OFF_SC   = OFF_QBK + (size_t)BB*NHQ;            // B*NK*NHQ
constexpr size_t OFF_MP   = OFF_SC  + (size_t)BB*NK*NHQ;         // B*16*NHQ
constexpr size_t OFF_SP   = OFF_MP  + (size_t)BB*16*NHQ;
constexpr size_t OFF_M    = OFF_SP  + (size_t)BB*16*NHQ;         // B*NHQ
constexpr size_t OFF_RS   = OFF_M   + (size_t)BB*NHQ;
constexpr size_t OFF_AVP  = OFF_RS  + (size_t)BB*NHQ;            // B*16*NHQ*C
constexpr size_t OFF_QATT = OFF_AVP + (size_t)BB*16*NHQ*CC;      // B*NQ*C
constexpr size_t OFF_UNC  = OFF_QATT+ (size_t)BB*NQn*CC;         // B*C
constexpr size_t OFF_REFT = OFF_UNC + (size_t)BB*CC;             // B*C
constexpr size_t OFF_RMAP = OFF_REFT+ (size_t)BB*CC;             // B*NK
constexpr size_t OFF_IDX  = OFF_RMAP+ (size_t)BB*NK;             // 128 ints
constexpr size_t OFF_RV   = OFF_IDX + 128;                       // 128 floats
constexpr size_t OFF_G    = OFF_RV  + 128;                       // B*NK*C

// T0: G[b][n][c] = keys[b][n][c] * guiding[b][c][n]  (LDS-tiled transpose)
__global__ __launch_bounds__(256) void t0_g(
    const float* __restrict__ keys, const float* __restrict__ guiding,
    float* __restrict__ ws)
{
  int bc = blockIdx.y; int b = bc >> 2; int c0 = (bc & 3) * 64;
  int n0 = blockIdx.x * 64; int t = threadIdx.x;
  __shared__ float Gt[64][65];   // [c_local][n_local], stride 65 -> conflict-free
  int lane = t & 63, grp = t >> 6;
  #pragma unroll
  for (int cc = 0; cc < 16; ++cc) {
    int c = grp*16 + cc;
    Gt[c][lane] = guiding[((size_t)b*CC + c0 + c)*NK + n0 + lane];
  }
  __syncthreads();
  float* G = ws + OFF_G;
  int c4 = (t & 15) * 4, rowg = t >> 4;
  #pragma unroll
  for (int p = 0; p < 4; ++p) {
    int row = p*16 + rowg;
    size_t base = ((size_t)b*NK + n0 + row)*CC + c0 + c4;
    float4 kv = *(const float4*)&keys[base];
    float4 o;
    o.x = kv.x * Gt[c4+0][row];
    o.y = kv.y * Gt[c4+1][row];
    o.z = kv.z * Gt[c4+2][row];
    o.w = kv.w * Gt[c4+3][row];
    *(float4*)&G[base] = o;
  }
}

// K1: qh = (queries+query_pe)@Wq+bq (scaled by 1/4); fold Wk,bk into query side
__global__ __launch_bounds__(256) void k1_qside(
    const float* __restrict__ queries, const float* __restrict__ query_pe,
    const float* __restrict__ Wq, const float* __restrict__ bq,
    const float* __restrict__ Wk, const float* __restrict__ bk,
    float* __restrict__ ws)
{
  int b = blockIdx.x >> 3, q = blockIdx.x & 7, t = threadIdx.x;
  __shared__ float x[CC];
  __shared__ float qh[CIn];
  x[t] = queries[(b*NQn+q)*CC + t] + query_pe[(b*NQn+q)*CC + t];
  __syncthreads();
  if (t < CIn) {
    float a = bq[t];
    for (int c = 0; c < CC; ++c) a += x[c]*Wq[c*CIn + t];
    qh[t] = a * 0.25f;
  }
  __syncthreads();
  float* Qk = ws + OFF_QK;
  #pragma unroll
  for (int h = 0; h < NHEADS; ++h) {
    float a = 0.f;
    #pragma unroll
    for (int d = 0; d < HDn; ++d) a += qh[h*HDn+d] * Wk[t*CIn + h*HDn + d];
    Qk[((size_t)b*CC + t)*NHQ + h*NQn + q] = a;
  }
  if (t < NHEADS) {
    float a = 0.f;
    #pragma unroll
    for (int d = 0; d < HDn; ++d) a += qh[t*HDn+d] * bk[t*HDn+d];
    (ws + OFF_QBK)[b*NHQ + t*NQn + q] = a;
  }
}

// K2: scores[b][k][hq] = sum_c (G+key_pe)[k,c] * Qk[c][hq] + qbk[hq]
__global__ __launch_bounds__(256) void k2_scores(
    const float* __restrict__ key_pe, float* __restrict__ ws)
{
  int b = blockIdx.y, n0 = blockIdx.x * 64, t = threadIdx.x;
  __shared__ __align__(16) float Xs[64][68];   // [k][c_local]
  __shared__ __align__(16) float Qs[64][64];   // [c_local][hq]
  const float* Qk = ws + OFF_QK;
  const float* G  = ws + OFF_G;
  int tx = t & 15, ty = t >> 4;
  int c4 = (t & 15)*4, rowg = t >> 4;
  float acc[4][4] = {};
  for (int c0 = 0; c0 < CC; c0 += 64) {
    __syncthreads();
    #pragma unroll
    for (int p = 0; p < 4; ++p) {
      int row = p*16 + rowg;
      size_t base = ((size_t)b*NK + n0 + row)*CC + c0 + c4;
      float4 gv = *(const float4*)&G[base];
      float4 pv = *(const float4*)&key_pe[base];
      float4 o; o.x = gv.x+pv.x; o.y = gv.y+pv.y; o.z = gv.z+pv.z; o.w = gv.w+pv.w;
      *(float4*)&Xs[row][c4] = o;
    }
    #pragma unroll
    for (int i = 0; i < 16; ++i) {
      int l = i*256 + t;
      Qs[l >> 6][l & 63] = Qk[((size_t)b*CC + c0 + (l>>6))*NHQ + (l & 63)];
    }
    __syncthreads();
    #pragma unroll 4
    for (int cb = 0; cb < 16; ++cb) {
      float4 xf[4], qf[4];
      #pragma unroll
      for (int i = 0; i < 4; ++i) xf[i] = *(const float4*)&Xs[4*ty+i][4*cb];
      #pragma unroll
      for (int u = 0; u < 4; ++u) qf[u] = *(const float4*)&Qs[4*cb+u][4*tx];
      #pragma unroll
      for (int u = 0; u < 4; ++u) {
        float xu[4] = { ((const float*)&xf[0])[u], ((const float*)&xf[1])[u],
                        ((const float*)&xf[2])[u], ((const float*)&xf[3])[u] };
        float qu[4] = { qf[u].x, qf[u].y, qf[u].z, qf[u].w };
        #pragma unroll
        for (int i = 0; i < 4; ++i)
          #pragma unroll
          for (int j = 0; j < 4; ++j) acc[i][j] += xu[i]*qu[j];
      }
    }
  }
  const float* qbk = ws + OFF_QBK + (size_t)b*NHQ;
  float qb[4] = {qbk[4*tx], qbk[4*tx+1], qbk[4*tx+2], qbk[4*tx+3]};
  float* sc = ws + OFF_SC + ((size_t)b*NK + n0)*NHQ;
  #pragma unroll
  for (int i = 0; i < 4; ++i) {
    float4 o;
    o.x = acc[i][0]+qb[0]; o.y = acc[i][1]+qb[1]; o.z = acc[i][2]+qb[2]; o.w = acc[i][3]+qb[3];
    *(float4*)&sc[(4*ty + i)*NHQ + 4*tx] = o;
  }
}

// K3a: per-(b, 256-k subblock) online (max, sumexp) partials per hq
__global__ __launch_bounds__(256) void k3a_stats(float* __restrict__ ws)
{
  int b = blockIdx.y, sb = blockIdx.x, t = threadIdx.x;
  int hq = t & 63, r = t >> 6;
  const float* sc = ws + OFF_SC + ((size_t)b*NK + sb*256)*NHQ;
  float m = -INFINITY, s = 0.f;
  for (int i = 0; i < 64; ++i) {
    float v = sc[(r + 4*i)*NHQ + hq];
    if (v > m) { s = s*expf(m - v) + 1.f; m = v; } else { s += expf(v - m); }
  }
  __shared__ float rm[256], rs[256];
  rm[t] = m; rs[t] = s;
  __syncthreads();
  if (t < 64) {
    float m0=rm[t], m1=rm[t+64], m2=rm[t+128], m3=rm[t+192];
    float mm = fmaxf(fmaxf(m0,m1), fmaxf(m2,m3));
    float ss = rs[t]*expf(m0-mm) + rs[t+64]*expf(m1-mm) + rs[t+128]*expf(m2-mm) + rs[t+192]*expf(m3-mm);
    (ws + OFF_MP)[(b*16 + sb)*NHQ + t] = mm;
    (ws + OFF_SP)[(b*16 + sb)*NHQ + t] = ss;
  }
}

// K3b: combine 16 partials -> m, 1/s per (b,hq)
__global__ __launch_bounds__(64) void k3b_combine(float* __restrict__ ws)
{
  int b = blockIdx.x, hq = threadIdx.x;
  const float* mp = ws + OFF_MP + (size_t)b*16*NHQ;
  const float* sp = ws + OFF_SP + (size_t)b*16*NHQ;
  float m = -INFINITY;
  #pragma unroll
  for (int i = 0; i < 16; ++i) m = fmaxf(m, mp[i*NHQ+hq]);
  float s = 0.f;
  #pragma unroll
  for (int i = 0; i < 16; ++i) s += sp[i*NHQ+hq]*expf(mp[i*NHQ+hq]-m);
  (ws+OFF_M)[b*NHQ+hq] = m;
  (ws+OFF_RS)[b*NHQ+hq] = 1.0f/s;
}

// K4: AVpart[b][kb][hq][c] = sum_{k in kb} attn[k,hq]*G[k,c]
__global__ __launch_bounds__(256) void k4_av(float* __restrict__ ws)
{
  int b = blockIdx.y, kb = blockIdx.x, t = threadIdx.x;
  int k0 = kb * 256;
  __shared__ __align__(16) float gld[32][260];
  __shared__ __align__(16) float wld[32][64];
  __shared__ float mv[64], rv[64];
  if (t < 64) { mv[t] = (ws+OFF_M)[b*NHQ+t]; rv[t] = (ws+OFF_RS)[b*NHQ+t]; }
  int th = t & 15, tc = t >> 4;
  float accf[4][16] = {};
  const float* sc = ws + OFF_SC;
  const float* G  = ws + OFF_G;
  for (int kk = 0; kk < 256; kk += 32) {
    __syncthreads();
    #pragma unroll
    for (int p = 0; p < 8; ++p) {
      int row = (t>>6) + 4*p;
      *(float4*)&gld[row][(t&63)*4] =
        *(const float4*)&G[((size_t)b*NK + k0+kk+row)*CC + (t&63)*4];
    }
    #pragma unroll
    for (int i = 0; i < 8; ++i) {
      int l = i*256 + t; int k = l >> 6, hq = l & 63;
      float v = sc[((size_t)b*NK + k0+kk+k)*NHQ + hq];
      wld[k][hq] = expf(v - mv[hq]) * rv[hq];
    }
    __syncthreads();
    for (int k = 0; k < 32; ++k) {
      float4 w4 = *(const float4*)&wld[k][4*th];
      float4 g0 = *(const float4*)&gld[k][16*tc];
      float4 g1 = *(const float4*)&gld[k][16*tc+4];
      float4 g2 = *(const float4*)&gld[k][16*tc+8];
      float4 g3 = *(const float4*)&gld[k][16*tc+12];
      float wq[4] = {w4.x, w4.y, w4.z, w4.w};
      float gq[16] = {g0.x,g0.y,g0.z,g0.w, g1.x,g1.y,g1.z,g1.w,
                      g2.x,g2.y,g2.z,g2.w, g3.x,g3.y,g3.z,g3.w};
      #pragma unroll
      for (int i = 0; i < 4; ++i)
        #pragma unroll
        for (int j = 0; j < 16; ++j) accf[i][j] += wq[i]*gq[j];
    }
  }
  float* avp = ws + OFF_AVP + (((size_t)b*16 + kb)*NHQ)*CC;
  #pragma unroll
  for (int i = 0; i < 4; ++i)
    #pragma unroll
    for (int j4 = 0; j4 < 4; ++j4) {
      float4 o;
      o.x = accf[i][4*j4]; o.y = accf[i][4*j4+1]; o.z = accf[i][4*j4+2]; o.w = accf[i][4*j4+3];
      *(float4*)&avp[(4*th + i)*CC + 16*tc + 4*j4] = o;
    }
}

// K56: reduce AVpart, then out = AV@Wv+bv (per head), queries_att = out@Wo+bo
__global__ __launch_bounds__(256) void k56_attout(
    const float* __restrict__ Wv, const float* __restrict__ bv,
    const float* __restrict__ Wo, const float* __restrict__ bo,
    float* __restrict__ ws)
{
  int b = blockIdx.x >> 3, q = blockIdx.x & 7, t = threadIdx.x;
  __shared__ float avs[NHEADS][CC];
  __shared__ float outv[CIn];
  const float* avp = ws + OFF_AVP;
  #pragma unroll
  for (int h = 0; h < NHEADS; ++h) {
    int hq = h*NQn + q;
    float a = 0.f;
    #pragma unroll 4
    for (int kb = 0; kb < 16; ++kb)
      a += avp[(((size_t)b*16 + kb)*NHQ + hq)*CC + t];
    avs[h][t] = a;
  }
  __syncthreads();
  if (t < CIn) {
    int h = t >> 4;
    float a = bv[t];
    for (int c = 0; c < CC; ++c) a += avs[h][c]*Wv[c*CIn + t];
    outv[t] = a;
  }
  __syncthreads();
  float a = bo[t];
  for (int ci = 0; ci < CIn; ++ci) a += outv[ci]*Wo[ci*CC + t];
  (ws+OFF_QATT)[((size_t)b*NQn + q)*CC + t] = a;
}

// K7: the two 3-layer MLPs on concat(static, q1)
__global__ __launch_bounds__(256) void k7_mlps(
    const float* __restrict__ su, const float* __restrict__ sr,
    const float* __restrict__ uW1, const float* __restrict__ ub1,
    const float* __restrict__ uW2, const float* __restrict__ ub2,
    const float* __restrict__ uW3, const float* __restrict__ ub3,
    const float* __restrict__ rW1, const float* __restrict__ rb1,
    const float* __restrict__ rW2, const float* __restrict__ rb2,
    const float* __restrict__ rW3, const float* __restrict__ rb3,
    float* __restrict__ ws)
{
  int b = blockIdx.x, t = threadIdx.x;
  __shared__ float xs[768];
  __shared__ float h1[2][64], h2[2][64];
  xs[t] = su[t];
  xs[256+t] = (ws+OFF_QATT)[((size_t)b*NQn + 1)*CC + t];
  xs[512+t] = sr[t];
  __syncthreads();
  if (t < 128) {
    int which = t >> 6, o = t & 63;
    const float* W1 = which ? rW1 : uW1;
    const float* b1 = which ? rb1 : ub1;
    int base = which ? 512 : 0;
    float a = b1[o];
    for (int i = 0; i < 256; ++i) a += xs[base+i]*W1[i*64 + o];
    for (int i = 0; i < 256; ++i) a += xs[256+i]*W1[(256+i)*64 + o];
    h1[which][o] = fmaxf(a, 0.f);
  }
  __syncthreads();
  if (t < 128) {
    int which = t >> 6, o = t & 63;
    const float* W2 = which ? rW2 : uW2;
    const float* b2 = which ? rb2 : ub2;
    float a = b2[o];
    #pragma unroll 8
    for (int i = 0; i < 64; ++i) a += h1[which][i]*W2[i*64+o];
    h2[which][o] = fmaxf(a, 0.f);
  }
  __syncthreads();
  {
    float a = ub3[t];
    #pragma unroll 8
    for (int i = 0; i < 64; ++i) a += h2[0][i]*uW3[i*CC + t];
    (ws+OFF_UNC)[b*CC + t] = a;
    float a2 = rb3[t];
    #pragma unroll 8
    for (int i = 0; i < 64; ++i) a2 += h2[1][i]*rW3[i*CC + t];
    (ws+OFF_REFT)[b*CC + t] = a2;
  }
}

// K8: three dots over c of G[b,n,:] with {q1, unc_tok, ref_tok}; ref_map
// one wave per n-row: 64 lanes x float4 = full 1KB row, butterfly reduce
__global__ __launch_bounds__(256) void k8_masks(float* __restrict__ ws)
{
  int b = blockIdx.y, t = threadIdx.x;
  int wave = t >> 6, lane = t & 63;
  __shared__ float q1s[CC], us[CC], rts[CC];
  q1s[t] = (ws+OFF_QATT)[((size_t)b*NQn+1)*CC + t];
  us[t]  = (ws+OFF_UNC)[b*CC + t];
  rts[t] = (ws+OFF_REFT)[b*CC + t];
  __syncthreads();
  float q1v[4], usv[4], rtv[4];
  #pragma unroll
  for (int u = 0; u < 4; ++u) {
    q1v[u] = q1s[lane*4+u]; usv[u] = us[lane*4+u]; rtv[u] = rts[lane*4+u];
  }
  const float* G = ws + OFF_G;
  float* rmap = ws + OFF_RMAP + (size_t)b*NK;
  int n_base = blockIdx.x*64 + wave*16;
  for (int r = 0; r < 16; ++r) {
    int n = n_base + r;
    float4 gv = *(const float4*)&G[((size_t)b*NK + n)*CC + lane*4];
    float aq = gv.x*q1v[0] + gv.y*q1v[1] + gv.z*q1v[2] + gv.w*q1v[3];
    float au = gv.x*usv[0] + gv.y*usv[1] + gv.z*usv[2] + gv.w*usv[3];
    float ar = gv.x*rtv[0] + gv.y*rtv[1] + gv.z*rtv[2] + gv.w*rtv[3];
    #pragma unroll
    for (int s = 1; s < 64; s <<= 1) {
      aq += __shfl_xor(aq, s, 64);
      au += __shfl_xor(au, s, 64);
      ar += __shfl_xor(ar, s, 64);
    }
    if (lane == 0) {
      float un = 1.f/(1.f+expf(-au));
      rmap[n] = un * (1.f/(1.f+expf(-ar)) - 1.f/(1.f+expf(-aq)));
    }
  }
}

// K9: gumbel-softmax iterative top-4 (replicates reference numerics in fp32)
__global__ __launch_bounds__(256) void k9_gumbel(
    const float* __restrict__ gp, const float* __restrict__ gn,
    float* __restrict__ ws)
{
  int sign = blockIdx.x, b = blockIdx.y, t = threadIdx.x;
  const float* noise = sign ? gn : gp;
  const float* rmap = ws + OFF_RMAP + (size_t)b*NK;
  float g[16], kh[16], oh[16];
  #pragma unroll
  for (int i = 0; i < 16; ++i) {
    int n = i*256 + t;
    float scv = rmap[n];
    if (sign) scv = -scv;
    g[i] = scv + noise[(size_t)b*NK + n];
    kh[i] = 0.f; oh[i] = 0.f;
  }
  __shared__ float rv[256];
  __shared__ int ri[256];
  for (int it = 0; it < 4; ++it) {
    if (it > 0) {
      #pragma unroll
      for (int i = 0; i < 16; ++i) g[i] += logf(fmaxf(1.f - oh[i], EPS_TINY));
    }
    float m = g[0];
    #pragma unroll
    for (int i = 1; i < 16; ++i) m = fmaxf(m, g[i]);
    rv[t] = m; __syncthreads();
    for (int s = 128; s > 0; s >>= 1) { if (t < s) rv[t] = fmaxf(rv[t], rv[t+s]); __syncthreads(); }
    m = rv[0]; __syncthreads();
    float e[16], ls = 0.f;
    #pragma unroll
    for (int i = 0; i < 16; ++i) { e[i] = expf(g[i]-m); ls += e[i]; }
    rv[t] = ls; __syncthreads();
    for (int s = 128; s > 0; s >>= 1) { if (t < s) rv[t] += rv[t+s]; __syncthreads(); }
    float ssum = rv[0]; __syncthreads();
    #pragma unroll
    for (int i = 0; i < 16; ++i) { oh[i] = e[i]/ssum; kh[i] += oh[i]; }
  }
  __shared__ int selI[4]; __shared__ float selR[4];
  for (int j = 0; j < 4; ++j) {
    float bvv = kh[0]; int bii = t;
    #pragma unroll
    for (int i = 1; i < 16; ++i) {
      if (kh[i] > bvv) { bvv = kh[i]; bii = i*256 + t; }
    }
    rv[t] = bvv; ri[t] = bii; __syncthreads();
    for (int s = 128; s > 0; s >>= 1) {
      if (t < s) {
        float v2 = rv[t+s]; int i2 = ri[t+s];
        if (v2 > rv[t] || (v2 == rv[t] && i2 < ri[t])) { rv[t] = v2; ri[t] = i2; }
      }
      __syncthreads();
    }
    int bidx = ri[0]; float bkh = rv[0];
    if (t == 0) { selI[j] = bidx; selR[j] = (1.f - bkh) + bkh; }
    if (t == (bidx & 255)) {
      int slot = bidx >> 8;
      #pragma unroll
      for (int i = 0; i < 16; ++i) if (i == slot) kh[i] = -1.f;
    }
    __syncthreads();
  }
  if (t == 0) {
    int id[4]; float rr[4];
    #pragma unroll
    for (int j = 0; j < 4; ++j) { id[j] = selI[j]; rr[j] = selR[j]; }
    for (int a = 0; a < 3; ++a)
      for (int c2 = a+1; c2 < 4; ++c2)
        if (id[c2] < id[a]) { int ti=id[a]; id[a]=id[c2]; id[c2]=ti; float tr=rr[a]; rr[a]=rr[c2]; rr[c2]=tr; }
    int* iout = (int*)(ws + OFF_IDX);
    float* rout = ws + OFF_RV;
    for (int j = 0; j < 4; ++j) {
      iout[(sign*BB + b)*4 + j] = id[j];
      rout[(sign*BB + b)*4 + j] = rr[j];
    }
  }
}

// K10: assemble (b, 32, 256) output
__global__ __launch_bounds__(256) void k10_out(
    const float* __restrict__ keys, const float* __restrict__ query_pe,
    const float* __restrict__ point_pos, const float* __restrict__ point_neg,
    const float* __restrict__ pe_gauss,
    float* __restrict__ ws, float* __restrict__ out)
{
  int b = blockIdx.y, r = blockIdx.x, t = threadIdx.x;
  const float* G = ws + OFF_G;
  float val;
  if (r < 8) {
    val = (r == 1) ? (ws+OFF_REFT)[b*CC + t]
                   : (ws+OFF_QATT)[((size_t)b*NQn + r)*CC + t];
  } else if (r < 16) {
    int j = r - 8; int sign = j >> 2; int jj = j & 3;
    int idx = ((const int*)(ws+OFF_IDX))[(sign*BB + b)*4 + jj];
    float rvv = (ws+OFF_RV)[(sign*BB + b)*4 + jj];
    float kv = keys[((size_t)b*NK + idx)*CC + t];
    float gv = G[((size_t)b*NK + idx)*CC + t];
    val = (kv + gv) * rvv;
  } else if (r < 24) {
    val = query_pe[((size_t)b*NQn + (r-16))*CC + t];
  } else {
    int j = r - 24; int sign = j >> 2; int jj = j & 3;
    int idx = ((const int*)(ws+OFF_IDX))[(sign*BB + b)*4 + jj];
    float rvv = (ws+OFF_RV)[(sign*BB + b)*4 + jj];
    const float* point = sign ? point_neg : point_pos;
    int h = idx >> 6, w = idx & 63;
    float x = (w + 0.5f)/64.f, y = (h + 0.5f)/64.f;
    int jf = (t < 128) ? t : (t - 128);
    float proj = ((2.f*x - 1.f)*pe_gauss[jf] + (2.f*y - 1.f)*pe_gauss[128 + jf]) * 6.28318530717958647692f;
    float sv = (t < 128) ? sinf(proj) : cosf(proj);
    val = sv*rvv + point[t];
  }
  out[((size_t)b*32 + r)*CC + t] = val;
}

extern "C" void kernel_launch(void* const* d_in, const int* in_sizes, int n_in,
                              void* d_out, int out_size, void* d_ws, size_t ws_size,
                              hipStream_t stream)
{
  const float* queries   = (const float*)d_in[0];
  const float* keys      = (const float*)d_in[1];
  const float* query_pe  = (const float*)d_in[2];
  const float* key_pe    = (const float*)d_in[3];
  const float* guiding   = (const float*)d_in[4];
  const float* gumbel_p  = (const float*)d_in[5];
  const float* gumbel_n  = (const float*)d_in[6];
  const float* s_unc     = (const float*)d_in[7];
  const float* s_ref     = (const float*)d_in[8];
  const float* Wq  = (const float*)d_in[9];   const float* bq  = (const float*)d_in[10];
  const float* Wk  = (const float*)d_in[11];  const float* bk  = (const float*)d_in[12];
  const float* Wv  = (const float*)d_in[13];  const float* bv  = (const float*)d_in[14];
  const float* Wo  = (const float*)d_in[15];  const float* bo  = (const float*)d_in[16];
  const float* uW1 = (const float*)d_in[17];  const float* ub1 = (const float*)d_in[18];
  const float* uW2 = (const float*)d_in[19];  const float* ub2 = (const float*)d_in[20];
  const float* uW3 = (const float*)d_in[21];  const float* ub3 = (const float*)d_in[22];
  const float* rW1 = (const float*)d_in[23];  const float* rb1 = (const float*)d_in[24];
  const float* rW2 = (const float*)d_in[25];  const float* rb2 = (const float*)d_in[26];
  const float* rW3 = (const float*)d_in[27];  const float* rb3 = (const float*)d_in[28];
  const float* pe_gauss  = (const float*)d_in[29];
  const float* point_pos = (const float*)d_in[30];
  const float* point_neg = (const float*)d_in[31];
  float* ws = (float*)d_ws;
  float* out = (float*)d_out;

  t0_g      <<<dim3(64, 64),  256, 0, stream>>>(keys, guiding, ws);
  k1_qside  <<<dim3(BB*NQn),  256, 0, stream>>>(queries, query_pe, Wq, bq, Wk, bk, ws);
  k2_scores <<<dim3(64, BB),  256, 0, stream>>>(key_pe, ws);
  k3a_stats <<<dim3(16, BB),  256, 0, stream>>>(ws);
  k3b_combine<<<dim3(BB),      64, 0, stream>>>(ws);
  k4_av     <<<dim3(16, BB),  256, 0, stream>>>(ws);
  k56_attout<<<dim3(BB*NQn),  256, 0, stream>>>(Wv, bv, Wo, bo, ws);
  k7_mlps   <<<dim3(BB),      256, 0, stream>>>(s_unc, s_ref, uW1, ub1, uW2, ub2, uW3, ub3,
                                                rW1, rb1, rW2, rb2, rW3, rb3, ws);
  k8_masks  <<<dim3(64, BB),  256, 0, stream>>>(ws);
  k9_gumbel <<<dim3(2, BB),   256, 0, stream>>>(gumbel_p, gumbel_n, ws);
  k10_out   <<<dim3(32, BB),  256, 0, stream>>>(keys, query_pe, point_pos, point_neg,
                                                pe_gauss, ws, out);
}

// Round 3
// 249.501 us; speedup vs baseline: 1.1642x; 1.0210x over previous
//
#include <hip/hip_runtime.h>

#define BB 16
#define NQn 8
#define NK 4096
#define CC 256
#define NHEADS 8
#define CIn 128
#define HDn 16
#define NHQ 64
#define EPS_TINY 1.17549435e-38f

// workspace float offsets
constexpr size_t OFF_QK   = 0;                                   // B*C*NHQ
constexpr size_t OFF_QBK  = OFF_QK  + (size_t)BB*CC*NHQ;         // B*NHQ
constexpr size_t OFF_SC   = OFF_QBK + (size_t)BB*NHQ;            // B*NK*NHQ
constexpr size_t OFF_MP   = OFF_SC  + (size_t)BB*NK*NHQ;         // B*16*NHQ
constexpr size_t OFF_SP   = OFF_MP  + (size_t)BB*16*NHQ;
constexpr size_t OFF_M    = OFF_SP  + (size_t)BB*16*NHQ;         // B*NHQ
constexpr size_t OFF_RS   = OFF_M   + (size_t)BB*NHQ;
constexpr size_t OFF_AVP  = OFF_RS  + (size_t)BB*NHQ;            // B*16*NHQ*C
constexpr size_t OFF_QATT = OFF_AVP + (size_t)BB*16*NHQ*CC;      // B*NQ*C
constexpr size_t OFF_UNC  = OFF_QATT+ (size_t)BB*NQn*CC;         // B*C
constexpr size_t OFF_REFT = OFF_UNC + (size_t)BB*CC;             // B*C
constexpr size_t OFF_RMAP = OFF_REFT+ (size_t)BB*CC;             // B*NK
constexpr size_t OFF_IDX  = OFF_RMAP+ (size_t)BB*NK;             // 128 ints
constexpr size_t OFF_RV   = OFF_IDX + 128;                       // 128 floats
constexpr size_t OFF_G    = OFF_RV  + 128;                       // B*NK*C

// K1: qh = (queries+query_pe)@Wq+bq (scaled by 1/4); fold Wk,bk into query side
__global__ __launch_bounds__(256) void k1_qside(
    const float* __restrict__ queries, const float* __restrict__ query_pe,
    const float* __restrict__ Wq, const float* __restrict__ bq,
    const float* __restrict__ Wk, const float* __restrict__ bk,
    float* __restrict__ ws)
{
  int b = blockIdx.x >> 3, q = blockIdx.x & 7, t = threadIdx.x;
  __shared__ float x[CC];
  __shared__ float qh[CIn];
  x[t] = queries[(b*NQn+q)*CC + t] + query_pe[(b*NQn+q)*CC + t];
  __syncthreads();
  if (t < CIn) {
    float a = bq[t];
    for (int c = 0; c < CC; ++c) a += x[c]*Wq[c*CIn + t];
    qh[t] = a * 0.25f;
  }
  __syncthreads();
  float* Qk = ws + OFF_QK;
  #pragma unroll
  for (int h = 0; h < NHEADS; ++h) {
    float a = 0.f;
    #pragma unroll
    for (int d = 0; d < HDn; ++d) a += qh[h*HDn+d] * Wk[t*CIn + h*HDn + d];
    Qk[((size_t)b*CC + t)*NHQ + h*NQn + q] = a;
  }
  if (t < NHEADS) {
    float a = 0.f;
    #pragma unroll
    for (int d = 0; d < HDn; ++d) a += qh[t*HDn+d] * bk[t*HDn+d];
    (ws + OFF_QBK)[b*NHQ + t*NQn + q] = a;
  }
}

// K2g: fused G-materialization + scores GEMM.
// G[b][n][c] = keys*guidingT (written to HBM for k4/k8/k10);
// scores[b][k][hq] = sum_c (G+key_pe)[k,c]*Qk[c][hq] + qbk[hq]
__global__ __launch_bounds__(256) void k2_scores(
    const float* __restrict__ keys, const float* __restrict__ key_pe,
    const float* __restrict__ guiding, float* __restrict__ ws)
{
  int b = blockIdx.y, n0 = blockIdx.x * 64, t = threadIdx.x;
  __shared__ __align__(16) float Xs[64][68];   // [k][c_local]
  __shared__ __align__(16) float Qs[64][64];   // [c_local][hq]
  __shared__ float Gt[64][65];                 // guiding transpose buffer
  const float* Qk = ws + OFF_QK;
  float* G = ws + OFF_G;
  int tx = t & 15, ty = t >> 4;
  int c4 = (t & 15)*4, rowg = t >> 4;
  int lane = t & 63, grp = t >> 6;
  float acc[4][4] = {};
  for (int c0 = 0; c0 < CC; c0 += 64) {
    __syncthreads();
    // phase 1: stage guiding transposed (coalesced along n) + Qs
    #pragma unroll
    for (int cc = 0; cc < 16; ++cc) {
      int c = grp*16 + cc;
      Gt[c][lane] = guiding[((size_t)b*CC + c0 + c)*NK + n0 + lane];
    }
    #pragma unroll
    for (int i = 0; i < 16; ++i) {
      int l = i*256 + t;
      Qs[l >> 6][l & 63] = Qk[((size_t)b*CC + c0 + (l>>6))*NHQ + (l & 63)];
    }
    __syncthreads();
    // phase 2: build Xs = keys*Gt + pe, write G to HBM
    #pragma unroll
    for (int p = 0; p < 4; ++p) {
      int row = p*16 + rowg;
      size_t base = ((size_t)b*NK + n0 + row)*CC + c0 + c4;
      float4 kv = *(const float4*)&keys[base];
      float4 pv = *(const float4*)&key_pe[base];
      float4 g4;
      g4.x = kv.x * Gt[c4+0][row];
      g4.y = kv.y * Gt[c4+1][row];
      g4.z = kv.z * Gt[c4+2][row];
      g4.w = kv.w * Gt[c4+3][row];
      *(float4*)&G[base] = g4;
      float4 o; o.x = g4.x+pv.x; o.y = g4.y+pv.y; o.z = g4.z+pv.z; o.w = g4.w+pv.w;
      *(float4*)&Xs[row][c4] = o;
    }
    __syncthreads();
    // phase 3: GEMM (identical to previous round)
    #pragma unroll 4
    for (int cb = 0; cb < 16; ++cb) {
      float4 xf[4], qf[4];
      #pragma unroll
      for (int i = 0; i < 4; ++i) xf[i] = *(const float4*)&Xs[4*ty+i][4*cb];
      #pragma unroll
      for (int u = 0; u < 4; ++u) qf[u] = *(const float4*)&Qs[4*cb+u][4*tx];
      #pragma unroll
      for (int u = 0; u < 4; ++u) {
        float xu[4] = { ((const float*)&xf[0])[u], ((const float*)&xf[1])[u],
                        ((const float*)&xf[2])[u], ((const float*)&xf[3])[u] };
        float qu[4] = { qf[u].x, qf[u].y, qf[u].z, qf[u].w };
        #pragma unroll
        for (int i = 0; i < 4; ++i)
          #pragma unroll
          for (int j = 0; j < 4; ++j) acc[i][j] += xu[i]*qu[j];
      }
    }
  }
  const float* qbk = ws + OFF_QBK + (size_t)b*NHQ;
  float qb[4] = {qbk[4*tx], qbk[4*tx+1], qbk[4*tx+2], qbk[4*tx+3]};
  float* sc = ws + OFF_SC + ((size_t)b*NK + n0)*NHQ;
  #pragma unroll
  for (int i = 0; i < 4; ++i) {
    float4 o;
    o.x = acc[i][0]+qb[0]; o.y = acc[i][1]+qb[1]; o.z = acc[i][2]+qb[2]; o.w = acc[i][3]+qb[3];
    *(float4*)&sc[(4*ty + i)*NHQ + 4*tx] = o;
  }
}

// K3a: per-(b, 256-k subblock) online (max, sumexp) partials per hq
__global__ __launch_bounds__(256) void k3a_stats(float* __restrict__ ws)
{
  int b = blockIdx.y, sb = blockIdx.x, t = threadIdx.x;
  int hq = t & 63, r = t >> 6;
  const float* sc = ws + OFF_SC + ((size_t)b*NK + sb*256)*NHQ;
  float m = -INFINITY, s = 0.f;
  for (int i = 0; i < 64; ++i) {
    float v = sc[(r + 4*i)*NHQ + hq];
    if (v > m) { s = s*expf(m - v) + 1.f; m = v; } else { s += expf(v - m); }
  }
  __shared__ float rm[256], rs[256];
  rm[t] = m; rs[t] = s;
  __syncthreads();
  if (t < 64) {
    float m0=rm[t], m1=rm[t+64], m2=rm[t+128], m3=rm[t+192];
    float mm = fmaxf(fmaxf(m0,m1), fmaxf(m2,m3));
    float ss = rs[t]*expf(m0-mm) + rs[t+64]*expf(m1-mm) + rs[t+128]*expf(m2-mm) + rs[t+192]*expf(m3-mm);
    (ws + OFF_MP)[(b*16 + sb)*NHQ + t] = mm;
    (ws + OFF_SP)[(b*16 + sb)*NHQ + t] = ss;
  }
}

// K3b: combine 16 partials -> m, 1/s per (b,hq)
__global__ __launch_bounds__(64) void k3b_combine(float* __restrict__ ws)
{
  int b = blockIdx.x, hq = threadIdx.x;
  const float* mp = ws + OFF_MP + (size_t)b*16*NHQ;
  const float* sp = ws + OFF_SP + (size_t)b*16*NHQ;
  float m = -INFINITY;
  #pragma unroll
  for (int i = 0; i < 16; ++i) m = fmaxf(m, mp[i*NHQ+hq]);
  float s = 0.f;
  #pragma unroll
  for (int i = 0; i < 16; ++i) s += sp[i*NHQ+hq]*expf(mp[i*NHQ+hq]-m);
  (ws+OFF_M)[b*NHQ+hq] = m;
  (ws+OFF_RS)[b*NHQ+hq] = 1.0f/s;
}

// K4: AVpart[b][kb][hq][c] = sum_{k in kb*256 block} attn[k,hq]*G[k,c]
// 512 threads (8 waves/CU), thread tile 8hq x 4c -> both LDS reads 8-way shared
__global__ __launch_bounds__(512) void k4_av(float* __restrict__ ws)
{
  int b = blockIdx.y, kb = blockIdx.x, t = threadIdx.x;
  int k0 = kb * 256;
  __shared__ __align__(16) float gld[32][260];
  __shared__ __align__(16) float wld[32][64];
  __shared__ float mv[64], rv[64];
  if (t < 64) { mv[t] = (ws+OFF_M)[b*NHQ+t]; rv[t] = (ws+OFF_RS)[b*NHQ+t]; }
  int hq0 = (t & 7) * 8, c0 = (t >> 3) * 4;
  float accf[8][4] = {};
  const float* sc = ws + OFF_SC;
  const float* G  = ws + OFF_G;
  for (int kk = 0; kk < 256; kk += 32) {
    __syncthreads();
    #pragma unroll
    for (int p = 0; p < 4; ++p) {
      int row = p*8 + (t>>6);
      *(float4*)&gld[row][(t&63)*4] =
        *(const float4*)&G[((size_t)b*NK + k0+kk+row)*CC + (t&63)*4];
    }
    #pragma unroll
    for (int i = 0; i < 4; ++i) {
      int l = i*512 + t; int k = l >> 6, hq = l & 63;
      float v = sc[((size_t)b*NK + k0+kk+k)*NHQ + hq];
      wld[k][hq] = expf(v - mv[hq]) * rv[hq];
    }
    __syncthreads();
    #pragma unroll 2
    for (int k = 0; k < 32; ++k) {
      float4 w0 = *(const float4*)&wld[k][hq0];
      float4 w1 = *(const float4*)&wld[k][hq0+4];
      float4 gv = *(const float4*)&gld[k][c0];
      float wq[8] = {w0.x,w0.y,w0.z,w0.w, w1.x,w1.y,w1.z,w1.w};
      float gq[4] = {gv.x,gv.y,gv.z,gv.w};
      #pragma unroll
      for (int i = 0; i < 8; ++i)
        #pragma unroll
        for (int j = 0; j < 4; ++j) accf[i][j] += wq[i]*gq[j];
    }
  }
  float* avp = ws + OFF_AVP + (((size_t)b*16 + kb)*NHQ)*CC;
  #pragma unroll
  for (int i = 0; i < 8; ++i) {
    float4 o;
    o.x = accf[i][0]; o.y = accf[i][1]; o.z = accf[i][2]; o.w = accf[i][3];
    *(float4*)&avp[(size_t)(hq0 + i)*CC + c0] = o;
  }
}

// K56: reduce AVpart, then out = AV@Wv+bv (per head), queries_att = out@Wo+bo
__global__ __launch_bounds__(256) void k56_attout(
    const float* __restrict__ Wv, const float* __restrict__ bv,
    const float* __restrict__ Wo, const float* __restrict__ bo,
    float* __restrict__ ws)
{
  int b = blockIdx.x >> 3, q = blockIdx.x & 7, t = threadIdx.x;
  __shared__ float avs[NHEADS][CC];
  __shared__ float outv[CIn];
  const float* avp = ws + OFF_AVP;
  #pragma unroll
  for (int h = 0; h < NHEADS; ++h) {
    int hq = h*NQn + q;
    float a = 0.f;
    #pragma unroll 4
    for (int kb = 0; kb < 16; ++kb)
      a += avp[(((size_t)b*16 + kb)*NHQ + hq)*CC + t];
    avs[h][t] = a;
  }
  __syncthreads();
  if (t < CIn) {
    int h = t >> 4;
    float a = bv[t];
    for (int c = 0; c < CC; ++c) a += avs[h][c]*Wv[c*CIn + t];
    outv[t] = a;
  }
  __syncthreads();
  float a = bo[t];
  for (int ci = 0; ci < CIn; ++ci) a += outv[ci]*Wo[ci*CC + t];
  (ws+OFF_QATT)[((size_t)b*NQn + q)*CC + t] = a;
}

// K7: the two 3-layer MLPs on concat(static, q1)
__global__ __launch_bounds__(256) void k7_mlps(
    const float* __restrict__ su, const float* __restrict__ sr,
    const float* __restrict__ uW1, const float* __restrict__ ub1,
    const float* __restrict__ uW2, const float* __restrict__ ub2,
    const float* __restrict__ uW3, const float* __restrict__ ub3,
    const float* __restrict__ rW1, const float* __restrict__ rb1,
    const float* __restrict__ rW2, const float* __restrict__ rb2,
    const float* __restrict__ rW3, const float* __restrict__ rb3,
    float* __restrict__ ws)
{
  int b = blockIdx.x, t = threadIdx.x;
  __shared__ float xs[768];
  __shared__ float h1[2][64], h2[2][64];
  xs[t] = su[t];
  xs[256+t] = (ws+OFF_QATT)[((size_t)b*NQn + 1)*CC + t];
  xs[512+t] = sr[t];
  __syncthreads();
  if (t < 128) {
    int which = t >> 6, o = t & 63;
    const float* W1 = which ? rW1 : uW1;
    const float* b1 = which ? rb1 : ub1;
    int base = which ? 512 : 0;
    float a = b1[o];
    for (int i = 0; i < 256; ++i) a += xs[base+i]*W1[i*64 + o];
    for (int i = 0; i < 256; ++i) a += xs[256+i]*W1[(256+i)*64 + o];
    h1[which][o] = fmaxf(a, 0.f);
  }
  __syncthreads();
  if (t < 128) {
    int which = t >> 6, o = t & 63;
    const float* W2 = which ? rW2 : uW2;
    const float* b2 = which ? rb2 : ub2;
    float a = b2[o];
    #pragma unroll 8
    for (int i = 0; i < 64; ++i) a += h1[which][i]*W2[i*64+o];
    h2[which][o] = fmaxf(a, 0.f);
  }
  __syncthreads();
  {
    float a = ub3[t];
    #pragma unroll 8
    for (int i = 0; i < 64; ++i) a += h2[0][i]*uW3[i*CC + t];
    (ws+OFF_UNC)[b*CC + t] = a;
    float a2 = rb3[t];
    #pragma unroll 8
    for (int i = 0; i < 64; ++i) a2 += h2[1][i]*rW3[i*CC + t];
    (ws+OFF_REFT)[b*CC + t] = a2;
  }
}

// K8: three dots over c of G[b,n,:] with {q1, unc_tok, ref_tok}; ref_map
__global__ __launch_bounds__(256) void k8_masks(float* __restrict__ ws)
{
  int b = blockIdx.y, t = threadIdx.x;
  int wave = t >> 6, lane = t & 63;
  __shared__ float q1s[CC], us[CC], rts[CC];
  q1s[t] = (ws+OFF_QATT)[((size_t)b*NQn+1)*CC + t];
  us[t]  = (ws+OFF_UNC)[b*CC + t];
  rts[t] = (ws+OFF_REFT)[b*CC + t];
  __syncthreads();
  float q1v[4], usv[4], rtv[4];
  #pragma unroll
  for (int u = 0; u < 4; ++u) {
    q1v[u] = q1s[lane*4+u]; usv[u] = us[lane*4+u]; rtv[u] = rts[lane*4+u];
  }
  const float* G = ws + OFF_G;
  float* rmap = ws + OFF_RMAP + (size_t)b*NK;
  int n_base = blockIdx.x*64 + wave*16;
  for (int r = 0; r < 16; ++r) {
    int n = n_base + r;
    float4 gv = *(const float4*)&G[((size_t)b*NK + n)*CC + lane*4];
    float aq = gv.x*q1v[0] + gv.y*q1v[1] + gv.z*q1v[2] + gv.w*q1v[3];
    float au = gv.x*usv[0] + gv.y*usv[1] + gv.z*usv[2] + gv.w*usv[3];
    float ar = gv.x*rtv[0] + gv.y*rtv[1] + gv.z*rtv[2] + gv.w*rtv[3];
    #pragma unroll
    for (int s = 1; s < 64; s <<= 1) {
      aq += __shfl_xor(aq, s, 64);
      au += __shfl_xor(au, s, 64);
      ar += __shfl_xor(ar, s, 64);
    }
    if (lane == 0) {
      float un = 1.f/(1.f+expf(-au));
      rmap[n] = un * (1.f/(1.f+expf(-ar)) - 1.f/(1.f+expf(-aq)));
    }
  }
}

// K9: gumbel-softmax iterative top-4 (replicates reference numerics in fp32)
__global__ __launch_bounds__(256) void k9_gumbel(
    const float* __restrict__ gp, const float* __restrict__ gn,
    float* __restrict__ ws)
{
  int sign = blockIdx.x, b = blockIdx.y, t = threadIdx.x;
  const float* noise = sign ? gn : gp;
  const float* rmap = ws + OFF_RMAP + (size_t)b*NK;
  float g[16], kh[16], oh[16];
  #pragma unroll
  for (int i = 0; i < 16; ++i) {
    int n = i*256 + t;
    float scv = rmap[n];
    if (sign) scv = -scv;
    g[i] = scv + noise[(size_t)b*NK + n];
    kh[i] = 0.f; oh[i] = 0.f;
  }
  __shared__ float rv[256];
  __shared__ int ri[256];
  for (int it = 0; it < 4; ++it) {
    if (it > 0) {
      #pragma unroll
      for (int i = 0; i < 16; ++i) g[i] += logf(fmaxf(1.f - oh[i], EPS_TINY));
    }
    float m = g[0];
    #pragma unroll
    for (int i = 1; i < 16; ++i) m = fmaxf(m, g[i]);
    rv[t] = m; __syncthreads();
    for (int s = 128; s > 0; s >>= 1) { if (t < s) rv[t] = fmaxf(rv[t], rv[t+s]); __syncthreads(); }
    m = rv[0]; __syncthreads();
    float e[16], ls = 0.f;
    #pragma unroll
    for (int i = 0; i < 16; ++i) { e[i] = expf(g[i]-m); ls += e[i]; }
    rv[t] = ls; __syncthreads();
    for (int s = 128; s > 0; s >>= 1) { if (t < s) rv[t] += rv[t+s]; __syncthreads(); }
    float ssum = rv[0]; __syncthreads();
    #pragma unroll
    for (int i = 0; i < 16; ++i) { oh[i] = e[i]/ssum; kh[i] += oh[i]; }
  }
  __shared__ int selI[4]; __shared__ float selR[4];
  for (int j = 0; j < 4; ++j) {
    float bvv = kh[0]; int bii = t;
    #pragma unroll
    for (int i = 1; i < 16; ++i) {
      if (kh[i] > bvv) { bvv = kh[i]; bii = i*256 + t; }
    }
    rv[t] = bvv; ri[t] = bii; __syncthreads();
    for (int s = 128; s > 0; s >>= 1) {
      if (t < s) {
        float v2 = rv[t+s]; int i2 = ri[t+s];
        if (v2 > rv[t] || (v2 == rv[t] && i2 < ri[t])) { rv[t] = v2; ri[t] = i2; }
      }
      __syncthreads();
    }
    int bidx = ri[0]; float bkh = rv[0];
    if (t == 0) { selI[j] = bidx; selR[j] = (1.f - bkh) + bkh; }
    if (t == (bidx & 255)) {
      int slot = bidx >> 8;
      #pragma unroll
      for (int i = 0; i < 16; ++i) if (i == slot) kh[i] = -1.f;
    }
    __syncthreads();
  }
  if (t == 0) {
    int id[4]; float rr[4];
    #pragma unroll
    for (int j = 0; j < 4; ++j) { id[j] = selI[j]; rr[j] = selR[j]; }
    for (int a = 0; a < 3; ++a)
      for (int c2 = a+1; c2 < 4; ++c2)
        if (id[c2] < id[a]) { int ti=id[a]; id[a]=id[c2]; id[c2]=ti; float tr=rr[a]; rr[a]=rr[c2]; rr[c2]=tr; }
    int* iout = (int*)(ws + OFF_IDX);
    float* rout = ws + OFF_RV;
    for (int j = 0; j < 4; ++j) {
      iout[(sign*BB + b)*4 + j] = id[j];
      rout[(sign*BB + b)*4 + j] = rr[j];
    }
  }
}

// K10: assemble (b, 32, 256) output
__global__ __launch_bounds__(256) void k10_out(
    const float* __restrict__ keys, const float* __restrict__ query_pe,
    const float* __restrict__ point_pos, const float* __restrict__ point_neg,
    const float* __restrict__ pe_gauss,
    float* __restrict__ ws, float* __restrict__ out)
{
  int b = blockIdx.y, r = blockIdx.x, t = threadIdx.x;
  const float* G = ws + OFF_G;
  float val;
  if (r < 8) {
    val = (r == 1) ? (ws+OFF_REFT)[b*CC + t]
                   : (ws+OFF_QATT)[((size_t)b*NQn + r)*CC + t];
  } else if (r < 16) {
    int j = r - 8; int sign = j >> 2; int jj = j & 3;
    int idx = ((const int*)(ws+OFF_IDX))[(sign*BB + b)*4 + jj];
    float rvv = (ws+OFF_RV)[(sign*BB + b)*4 + jj];
    float kv = keys[((size_t)b*NK + idx)*CC + t];
    float gv = G[((size_t)b*NK + idx)*CC + t];
    val = (kv + gv) * rvv;
  } else if (r < 24) {
    val = query_pe[((size_t)b*NQn + (r-16))*CC + t];
  } else {
    int j = r - 24; int sign = j >> 2; int jj = j & 3;
    int idx = ((const int*)(ws+OFF_IDX))[(sign*BB + b)*4 + jj];
    float rvv = (ws+OFF_RV)[(sign*BB + b)*4 + jj];
    const float* point = sign ? point_neg : point_pos;
    int h = idx >> 6, w = idx & 63;
    float x = (w + 0.5f)/64.f, y = (h + 0.5f)/64.f;
    int jf = (t < 128) ? t : (t - 128);
    float proj = ((2.f*x - 1.f)*pe_gauss[jf] + (2.f*y - 1.f)*pe_gauss[128 + jf]) * 6.28318530717958647692f;
    float sv = (t < 128) ? sinf(proj) : cosf(proj);
    val = sv*rvv + point[t];
  }
  out[((size_t)b*32 + r)*CC + t] = val;
}

extern "C" void kernel_launch(void* const* d_in, const int* in_sizes, int n_in,
                              void* d_out, int out_size, void* d_ws, size_t ws_size,
                              hipStream_t stream)
{
  const float* queries   = (const float*)d_in[0];
  const float* keys      = (const float*)d_in[1];
  const float* query_pe  = (const float*)d_in[2];
  const float* key_pe    = (const float*)d_in[3];
  const float* guiding   = (const float*)d_in[4];
  const float* gumbel_p  = (const float*)d_in[5];
  const float* gumbel_n  = (const float*)d_in[6];
  const float* s_unc     = (const float*)d_in[7];
  const float* s_ref     = (const float*)d_in[8];
  const float* Wq  = (const float*)d_in[9];   const float* bq  = (const float*)d_in[10];
  const float* Wk  = (const float*)d_in[11];  const float* bk  = (const float*)d_in[12];
  const float* Wv  = (const float*)d_in[13];  const float* bv  = (const float*)d_in[14];
  const float* Wo  = (const float*)d_in[15];  const float* bo  = (const float*)d_in[16];
  const float* uW1 = (const float*)d_in[17];  const float* ub1 = (const float*)d_in[18];
  const float* uW2 = (const float*)d_in[19];  const float* ub2 = (const float*)d_in[20];
  const float* uW3 = (const float*)d_in[21];  const float* ub3 = (const float*)d_in[22];
  const float* rW1 = (const float*)d_in[23];  const float* rb1 = (const float*)d_in[24];
  const float* rW2 = (const float*)d_in[25];  const float* rb2 = (const float*)d_in[26];
  const float* rW3 = (const float*)d_in[27];  const float* rb3 = (const float*)d_in[28];
  const float* pe_gauss  = (const float*)d_in[29];
  const float* point_pos = (const float*)d_in[30];
  const float* point_neg = (const float*)d_in[31];
  float* ws = (float*)d_ws;
  float* out = (float*)d_out;

  k1_qside  <<<dim3(BB*NQn),  256, 0, stream>>>(queries, query_pe, Wq, bq, Wk, bk, ws);
  k2_scores <<<dim3(64, BB),  256, 0, stream>>>(keys, key_pe, guiding, ws);
  k3a_stats <<<dim3(16, BB),  256, 0, stream>>>(ws);
  k3b_combine<<<dim3(BB),      64, 0, stream>>>(ws);
  k4_av     <<<dim3(16, BB),  512, 0, stream>>>(ws);
  k56_attout<<<dim3(BB*NQn),  256, 0, stream>>>(Wv, bv, Wo, bo, ws);
  k7_mlps   <<<dim3(BB),      256, 0, stream>>>(s_unc, s_ref, uW1, ub1, uW2, ub2, uW3, ub3,
                                                rW1, rb1, rW2, rb2, rW3, rb3, ws);
  k8_masks  <<<dim3(64, BB),  256, 0, stream>>>(ws);
  k9_gumbel <<<dim3(2, BB),   256, 0, stream>>>(gumbel_p, gumbel_n, ws);
  k10_out   <<<dim3(32, BB),  256, 0, stream>>>(keys, query_pe, point_pos, point_neg,
                                                pe_gauss, ws, out);
}

// Round 4
// 243.345 us; speedup vs baseline: 1.1937x; 1.0253x over previous
//
#include <hip/hip_runtime.h>

#define BB 16
#define NQn 8
#define NK 4096
#define CC 256
#define NHEADS 8
#define CIn 128
#define HDn 16
#define NHQ 64
#define EPS_TINY 1.17549435e-38f

// workspace float offsets
constexpr size_t OFF_QK   = 0;                                   // B*C*NHQ
constexpr size_t OFF_QBK  = OFF_QK  + (size_t)BB*CC*NHQ;         // B*NHQ
constexpr size_t OFF_SC   = OFF_QBK + (size_t)BB*NHQ;            // B*NK*NHQ
constexpr size_t OFF_MP   = OFF_SC  + (size_t)BB*NK*NHQ;         // B*16*NHQ
constexpr size_t OFF_SP   = OFF_MP  + (size_t)BB*16*NHQ;
constexpr size_t OFF_M    = OFF_SP  + (size_t)BB*16*NHQ;         // B*NHQ
constexpr size_t OFF_RS   = OFF_M   + (size_t)BB*NHQ;
constexpr size_t OFF_AVP  = OFF_RS  + (size_t)BB*NHQ;            // B*16*NHQ*C
constexpr size_t OFF_QATT = OFF_AVP + (size_t)BB*16*NHQ*CC;      // B*NQ*C
constexpr size_t OFF_UNC  = OFF_QATT+ (size_t)BB*NQn*CC;         // B*C
constexpr size_t OFF_REFT = OFF_UNC + (size_t)BB*CC;             // B*C
constexpr size_t OFF_RMAP = OFF_REFT+ (size_t)BB*CC;             // B*NK
constexpr size_t OFF_IDX  = OFF_RMAP+ (size_t)BB*NK;             // 128 ints
constexpr size_t OFF_RV   = OFF_IDX + 128;                       // 128 floats
constexpr size_t OFF_G    = OFF_RV  + 128;                       // B*NK*C

// K1: qh = (queries+query_pe)@Wq+bq (scaled by 1/4); fold Wk,bk into query side
__global__ __launch_bounds__(256) void k1_qside(
    const float* __restrict__ queries, const float* __restrict__ query_pe,
    const float* __restrict__ Wq, const float* __restrict__ bq,
    const float* __restrict__ Wk, const float* __restrict__ bk,
    float* __restrict__ ws)
{
  int b = blockIdx.x >> 3, q = blockIdx.x & 7, t = threadIdx.x;
  __shared__ float x[CC];
  __shared__ float qh[CIn];
  x[t] = queries[(b*NQn+q)*CC + t] + query_pe[(b*NQn+q)*CC + t];
  __syncthreads();
  if (t < CIn) {
    float a = bq[t];
    for (int c = 0; c < CC; ++c) a += x[c]*Wq[c*CIn + t];
    qh[t] = a * 0.25f;
  }
  __syncthreads();
  float* Qk = ws + OFF_QK;
  #pragma unroll
  for (int h = 0; h < NHEADS; ++h) {
    float a = 0.f;
    #pragma unroll
    for (int d = 0; d < HDn; ++d) a += qh[h*HDn+d] * Wk[t*CIn + h*HDn + d];
    Qk[((size_t)b*CC + t)*NHQ + h*NQn + q] = a;
  }
  if (t < NHEADS) {
    float a = 0.f;
    #pragma unroll
    for (int d = 0; d < HDn; ++d) a += qh[t*HDn+d] * bk[t*HDn+d];
    (ws + OFF_QBK)[b*NHQ + t*NQn + q] = a;
  }
}

// K2: fused G-materialization + scores GEMM, software-pipelined (2 barriers/chunk,
// all global loads prefetched to registers one chunk ahead).
__global__ __launch_bounds__(256) void k2_scores(
    const float* __restrict__ keys, const float* __restrict__ key_pe,
    const float* __restrict__ guiding, float* __restrict__ ws)
{
  int b = blockIdx.y, n0 = blockIdx.x * 64, t = threadIdx.x;
  __shared__ __align__(16) float Xs[64][68];   // [k][c_local]
  __shared__ __align__(16) float Qs[64][64];   // [c_local][hq]
  __shared__ float Gt[64][65];                 // guiding transpose buffer
  const float* Qk = ws + OFF_QK;
  float* G = ws + OFF_G;
  int tx = t & 15, ty = t >> 4;
  int c4 = tx*4, rowg = ty;
  int lane = t & 63, grp = t >> 6;
  float acc[4][4] = {};

  float gpref[16];
  float4 kpref[4], ppref[4];
  float qpref[16];
  // prologue: prefetch chunk 0
  #pragma unroll
  for (int cc = 0; cc < 16; ++cc)
    gpref[cc] = guiding[((size_t)b*CC + grp*16+cc)*NK + n0 + lane];
  #pragma unroll
  for (int p = 0; p < 4; ++p) {
    size_t base = ((size_t)b*NK + n0 + p*16+rowg)*CC + c4;
    kpref[p] = *(const float4*)&keys[base];
    ppref[p] = *(const float4*)&key_pe[base];
  }
  #pragma unroll
  for (int i = 0; i < 16; ++i) {
    int l = i*256 + t;
    qpref[i] = Qk[((size_t)b*CC + (l>>6))*NHQ + (l & 63)];
  }

  for (int c0 = 0; c0 < CC; c0 += 64) {
    // P1: commit Gt from registers
    #pragma unroll
    for (int cc = 0; cc < 16; ++cc) Gt[grp*16+cc][lane] = gpref[cc];
    __syncthreads();
    // P2: commit Qs; build Xs = keys*Gt + pe; write G to HBM
    #pragma unroll
    for (int i = 0; i < 16; ++i) {
      int l = i*256 + t;
      Qs[l >> 6][l & 63] = qpref[i];
    }
    #pragma unroll
    for (int p = 0; p < 4; ++p) {
      int row = p*16 + rowg;
      size_t base = ((size_t)b*NK + n0 + row)*CC + c0 + c4;
      float4 kv = kpref[p], pv = ppref[p];
      float4 g4;
      g4.x = kv.x * Gt[c4+0][row];
      g4.y = kv.y * Gt[c4+1][row];
      g4.z = kv.z * Gt[c4+2][row];
      g4.w = kv.w * Gt[c4+3][row];
      *(float4*)&G[base] = g4;
      float4 o; o.x = g4.x+pv.x; o.y = g4.y+pv.y; o.z = g4.z+pv.z; o.w = g4.w+pv.w;
      *(float4*)&Xs[row][c4] = o;
    }
    __syncthreads();
    // P3: prefetch next chunk (latency hidden under GEMM), then GEMM
    if (c0 + 64 < CC) {
      int c1 = c0 + 64;
      #pragma unroll
      for (int cc = 0; cc < 16; ++cc)
        gpref[cc] = guiding[((size_t)b*CC + c1 + grp*16+cc)*NK + n0 + lane];
      #pragma unroll
      for (int p = 0; p < 4; ++p) {
        size_t base = ((size_t)b*NK + n0 + p*16+rowg)*CC + c1 + c4;
        kpref[p] = *(const float4*)&keys[base];
        ppref[p] = *(const float4*)&key_pe[base];
      }
      #pragma unroll
      for (int i = 0; i < 16; ++i) {
        int l = i*256 + t;
        qpref[i] = Qk[((size_t)b*CC + c1 + (l>>6))*NHQ + (l & 63)];
      }
    }
    #pragma unroll 4
    for (int cb = 0; cb < 16; ++cb) {
      float4 xf[4], qf[4];
      #pragma unroll
      for (int i = 0; i < 4; ++i) xf[i] = *(const float4*)&Xs[4*ty+i][4*cb];
      #pragma unroll
      for (int u = 0; u < 4; ++u) qf[u] = *(const float4*)&Qs[4*cb+u][4*tx];
      #pragma unroll
      for (int u = 0; u < 4; ++u) {
        float xu[4] = { ((const float*)&xf[0])[u], ((const float*)&xf[1])[u],
                        ((const float*)&xf[2])[u], ((const float*)&xf[3])[u] };
        float qu[4] = { qf[u].x, qf[u].y, qf[u].z, qf[u].w };
        #pragma unroll
        for (int i = 0; i < 4; ++i)
          #pragma unroll
          for (int j = 0; j < 4; ++j) acc[i][j] += xu[i]*qu[j];
      }
    }
  }
  const float* qbk = ws + OFF_QBK + (size_t)b*NHQ;
  float qb[4] = {qbk[4*tx], qbk[4*tx+1], qbk[4*tx+2], qbk[4*tx+3]};
  float* sc = ws + OFF_SC + ((size_t)b*NK + n0)*NHQ;
  #pragma unroll
  for (int i = 0; i < 4; ++i) {
    float4 o;
    o.x = acc[i][0]+qb[0]; o.y = acc[i][1]+qb[1]; o.z = acc[i][2]+qb[2]; o.w = acc[i][3]+qb[3];
    *(float4*)&sc[(4*ty + i)*NHQ + 4*tx] = o;
  }
}

// K3a: per-(b, 256-k subblock) online (max, sumexp) partials per hq
__global__ __launch_bounds__(256) void k3a_stats(float* __restrict__ ws)
{
  int b = blockIdx.y, sb = blockIdx.x, t = threadIdx.x;
  int hq = t & 63, r = t >> 6;
  const float* sc = ws + OFF_SC + ((size_t)b*NK + sb*256)*NHQ;
  float m = -INFINITY, s = 0.f;
  for (int i = 0; i < 64; ++i) {
    float v = sc[(r + 4*i)*NHQ + hq];
    if (v > m) { s = s*expf(m - v) + 1.f; m = v; } else { s += expf(v - m); }
  }
  __shared__ float rm[256], rs[256];
  rm[t] = m; rs[t] = s;
  __syncthreads();
  if (t < 64) {
    float m0=rm[t], m1=rm[t+64], m2=rm[t+128], m3=rm[t+192];
    float mm = fmaxf(fmaxf(m0,m1), fmaxf(m2,m3));
    float ss = rs[t]*expf(m0-mm) + rs[t+64]*expf(m1-mm) + rs[t+128]*expf(m2-mm) + rs[t+192]*expf(m3-mm);
    (ws + OFF_MP)[(b*16 + sb)*NHQ + t] = mm;
    (ws + OFF_SP)[(b*16 + sb)*NHQ + t] = ss;
  }
}

// K3b: combine 16 partials -> m, 1/s per (b,hq)
__global__ __launch_bounds__(64) void k3b_combine(float* __restrict__ ws)
{
  int b = blockIdx.x, hq = threadIdx.x;
  const float* mp = ws + OFF_MP + (size_t)b*16*NHQ;
  const float* sp = ws + OFF_SP + (size_t)b*16*NHQ;
  float m = -INFINITY;
  #pragma unroll
  for (int i = 0; i < 16; ++i) m = fmaxf(m, mp[i*NHQ+hq]);
  float s = 0.f;
  #pragma unroll
  for (int i = 0; i < 16; ++i) s += sp[i*NHQ+hq]*expf(mp[i*NHQ+hq]-m);
  (ws+OFF_M)[b*NHQ+hq] = m;
  (ws+OFF_RS)[b*NHQ+hq] = 1.0f/s;
}

// K4: AVpart[b][kb][hq][c] = sum_k attn[k,hq]*G[k,c]; software-pipelined staging
__global__ __launch_bounds__(512) void k4_av(float* __restrict__ ws)
{
  int b = blockIdx.y, kb = blockIdx.x, t = threadIdx.x;
  int k0 = kb * 256;
  __shared__ __align__(16) float gld[32][260];
  __shared__ __align__(16) float wld[32][64];
  __shared__ float mv[64], rv[64];
  if (t < 64) { mv[t] = (ws+OFF_M)[b*NHQ+t]; rv[t] = (ws+OFF_RS)[b*NHQ+t]; }
  int hq0 = (t & 7) * 8, c0 = (t >> 3) * 4;
  float accf[8][4] = {};
  const float* sc = ws + OFF_SC;
  const float* G  = ws + OFF_G;
  // prologue: prefetch kk=0
  float4 gpref[4]; float spref[4];
  #pragma unroll
  for (int p = 0; p < 4; ++p) {
    int row = p*8 + (t>>6);
    gpref[p] = *(const float4*)&G[((size_t)b*NK + k0 + row)*CC + (t&63)*4];
  }
  #pragma unroll
  for (int i = 0; i < 4; ++i) {
    int l = i*512 + t;
    spref[i] = sc[((size_t)b*NK + k0 + (l>>6))*NHQ + (l&63)];
  }
  __syncthreads();   // mv/rv ready
  for (int kk = 0; kk < 256; kk += 32) {
    // P1: commit LDS from registers
    #pragma unroll
    for (int p = 0; p < 4; ++p) {
      int row = p*8 + (t>>6);
      *(float4*)&gld[row][(t&63)*4] = gpref[p];
    }
    #pragma unroll
    for (int i = 0; i < 4; ++i) {
      int l = i*512 + t; int k = l >> 6, hq = l & 63;
      wld[k][hq] = expf(spref[i] - mv[hq]) * rv[hq];
    }
    __syncthreads();
    // P2: prefetch next tile, then FMA
    if (kk + 32 < 256) {
      #pragma unroll
      for (int p = 0; p < 4; ++p) {
        int row = p*8 + (t>>6);
        gpref[p] = *(const float4*)&G[((size_t)b*NK + k0 + kk+32 + row)*CC + (t&63)*4];
      }
      #pragma unroll
      for (int i = 0; i < 4; ++i) {
        int l = i*512 + t;
        spref[i] = sc[((size_t)b*NK + k0 + kk+32 + (l>>6))*NHQ + (l&63)];
      }
    }
    #pragma unroll 2
    for (int k = 0; k < 32; ++k) {
      float4 w0 = *(const float4*)&wld[k][hq0];
      float4 w1 = *(const float4*)&wld[k][hq0+4];
      float4 gv = *(const float4*)&gld[k][c0];
      float wq[8] = {w0.x,w0.y,w0.z,w0.w, w1.x,w1.y,w1.z,w1.w};
      float gq[4] = {gv.x,gv.y,gv.z,gv.w};
      #pragma unroll
      for (int i = 0; i < 8; ++i)
        #pragma unroll
        for (int j = 0; j < 4; ++j) accf[i][j] += wq[i]*gq[j];
    }
    __syncthreads();
  }
  float* avp = ws + OFF_AVP + (((size_t)b*16 + kb)*NHQ)*CC;
  #pragma unroll
  for (int i = 0; i < 8; ++i) {
    float4 o;
    o.x = accf[i][0]; o.y = accf[i][1]; o.z = accf[i][2]; o.w = accf[i][3];
    *(float4*)&avp[(size_t)(hq0 + i)*CC + c0] = o;
  }
}

// K56: reduce AVpart, then out = AV@Wv+bv (per head), queries_att = out@Wo+bo
__global__ __launch_bounds__(256) void k56_attout(
    const float* __restrict__ Wv, const float* __restrict__ bv,
    const float* __restrict__ Wo, const float* __restrict__ bo,
    float* __restrict__ ws)
{
  int b = blockIdx.x >> 3, q = blockIdx.x & 7, t = threadIdx.x;
  __shared__ float avs[NHEADS][CC];
  __shared__ float outv[CIn];
  const float* avp = ws + OFF_AVP;
  #pragma unroll
  for (int h = 0; h < NHEADS; ++h) {
    int hq = h*NQn + q;
    float a = 0.f;
    #pragma unroll 4
    for (int kb = 0; kb < 16; ++kb)
      a += avp[(((size_t)b*16 + kb)*NHQ + hq)*CC + t];
    avs[h][t] = a;
  }
  __syncthreads();
  if (t < CIn) {
    int h = t >> 4;
    float a = bv[t];
    for (int c = 0; c < CC; ++c) a += avs[h][c]*Wv[c*CIn + t];
    outv[t] = a;
  }
  __syncthreads();
  float a = bo[t];
  for (int ci = 0; ci < CIn; ++ci) a += outv[ci]*Wo[ci*CC + t];
  (ws+OFF_QATT)[((size_t)b*NQn + q)*CC + t] = a;
}

// K7: the two 3-layer MLPs on concat(static, q1)
__global__ __launch_bounds__(256) void k7_mlps(
    const float* __restrict__ su, const float* __restrict__ sr,
    const float* __restrict__ uW1, const float* __restrict__ ub1,
    const float* __restrict__ uW2, const float* __restrict__ ub2,
    const float* __restrict__ uW3, const float* __restrict__ ub3,
    const float* __restrict__ rW1, const float* __restrict__ rb1,
    const float* __restrict__ rW2, const float* __restrict__ rb2,
    const float* __restrict__ rW3, const float* __restrict__ rb3,
    float* __restrict__ ws)
{
  int b = blockIdx.x, t = threadIdx.x;
  __shared__ float xs[768];
  __shared__ float h1[2][64], h2[2][64];
  xs[t] = su[t];
  xs[256+t] = (ws+OFF_QATT)[((size_t)b*NQn + 1)*CC + t];
  xs[512+t] = sr[t];
  __syncthreads();
  if (t < 128) {
    int which = t >> 6, o = t & 63;
    const float* W1 = which ? rW1 : uW1;
    const float* b1 = which ? rb1 : ub1;
    int base = which ? 512 : 0;
    float a = b1[o];
    for (int i = 0; i < 256; ++i) a += xs[base+i]*W1[i*64 + o];
    for (int i = 0; i < 256; ++i) a += xs[256+i]*W1[(256+i)*64 + o];
    h1[which][o] = fmaxf(a, 0.f);
  }
  __syncthreads();
  if (t < 128) {
    int which = t >> 6, o = t & 63;
    const float* W2 = which ? rW2 : uW2;
    const float* b2 = which ? rb2 : ub2;
    float a = b2[o];
    #pragma unroll 8
    for (int i = 0; i < 64; ++i) a += h1[which][i]*W2[i*64+o];
    h2[which][o] = fmaxf(a, 0.f);
  }
  __syncthreads();
  {
    float a = ub3[t];
    #pragma unroll 8
    for (int i = 0; i < 64; ++i) a += h2[0][i]*uW3[i*CC + t];
    (ws+OFF_UNC)[b*CC + t] = a;
    float a2 = rb3[t];
    #pragma unroll 8
    for (int i = 0; i < 64; ++i) a2 += h2[1][i]*rW3[i*CC + t];
    (ws+OFF_REFT)[b*CC + t] = a2;
  }
}

// K8: three dots over c of G[b,n,:] with {q1, unc_tok, ref_tok}; ref_map
__global__ __launch_bounds__(256) void k8_masks(float* __restrict__ ws)
{
  int b = blockIdx.y, t = threadIdx.x;
  int wave = t >> 6, lane = t & 63;
  __shared__ float q1s[CC], us[CC], rts[CC];
  q1s[t] = (ws+OFF_QATT)[((size_t)b*NQn+1)*CC + t];
  us[t]  = (ws+OFF_UNC)[b*CC + t];
  rts[t] = (ws+OFF_REFT)[b*CC + t];
  __syncthreads();
  float q1v[4], usv[4], rtv[4];
  #pragma unroll
  for (int u = 0; u < 4; ++u) {
    q1v[u] = q1s[lane*4+u]; usv[u] = us[lane*4+u]; rtv[u] = rts[lane*4+u];
  }
  const float* G = ws + OFF_G;
  float* rmap = ws + OFF_RMAP + (size_t)b*NK;
  int n_base = blockIdx.x*64 + wave*16;
  for (int r = 0; r < 16; ++r) {
    int n = n_base + r;
    float4 gv = *(const float4*)&G[((size_t)b*NK + n)*CC + lane*4];
    float aq = gv.x*q1v[0] + gv.y*q1v[1] + gv.z*q1v[2] + gv.w*q1v[3];
    float au = gv.x*usv[0] + gv.y*usv[1] + gv.z*usv[2] + gv.w*usv[3];
    float ar = gv.x*rtv[0] + gv.y*rtv[1] + gv.z*rtv[2] + gv.w*rtv[3];
    #pragma unroll
    for (int s = 1; s < 64; s <<= 1) {
      aq += __shfl_xor(aq, s, 64);
      au += __shfl_xor(au, s, 64);
      ar += __shfl_xor(ar, s, 64);
    }
    if (lane == 0) {
      float un = 1.f/(1.f+expf(-au));
      rmap[n] = un * (1.f/(1.f+expf(-ar)) - 1.f/(1.f+expf(-aq)));
    }
  }
}

// K9: gumbel-softmax iterative top-4; wave-shfl reductions (12 barriers total)
__global__ __launch_bounds__(256) void k9_gumbel(
    const float* __restrict__ gp, const float* __restrict__ gn,
    float* __restrict__ ws)
{
  int sign = blockIdx.x, b = blockIdx.y, t = threadIdx.x;
  int wave = t >> 6, lane = t & 63;
  const float* noise = sign ? gn : gp;
  const float* rmap = ws + OFF_RMAP + (size_t)b*NK;
  float g[16], kh[16], oh[16];
  #pragma unroll
  for (int i = 0; i < 16; ++i) {
    int n = i*256 + t;
    float scv = rmap[n];
    if (sign) scv = -scv;
    g[i] = scv + noise[(size_t)b*NK + n];
    kh[i] = 0.f; oh[i] = 0.f;
  }
  __shared__ float wred[8];        // [0..3]=max partials, [4..7]=sum partials
  __shared__ float selV[16];       // per selection round j: 4 wave partials
  __shared__ int   selIdx[16];
  for (int it = 0; it < 4; ++it) {
    if (it > 0) {
      #pragma unroll
      for (int i = 0; i < 16; ++i) g[i] += logf(fmaxf(1.f - oh[i], EPS_TINY));
    }
    float m = g[0];
    #pragma unroll
    for (int i = 1; i < 16; ++i) m = fmaxf(m, g[i]);
    #pragma unroll
    for (int s = 1; s < 64; s <<= 1) m = fmaxf(m, __shfl_xor(m, s, 64));
    if (lane == 0) wred[wave] = m;
    __syncthreads();
    m = fmaxf(fmaxf(wred[0], wred[1]), fmaxf(wred[2], wred[3]));
    float e[16], ls = 0.f;
    #pragma unroll
    for (int i = 0; i < 16; ++i) { e[i] = expf(g[i]-m); ls += e[i]; }
    #pragma unroll
    for (int s = 1; s < 64; s <<= 1) ls += __shfl_xor(ls, s, 64);
    if (lane == 0) wred[4+wave] = ls;
    __syncthreads();
    float ssum = wred[4]+wred[5]+wred[6]+wred[7];
    #pragma unroll
    for (int i = 0; i < 16; ++i) { oh[i] = e[i]/ssum; kh[i] += oh[i]; }
  }
  // selection: 4 rounds of global argmax (min-index tie-break), then exclude
  int id[4]; float rr[4];
  for (int j = 0; j < 4; ++j) {
    float bv = kh[0]; int bi = t;
    #pragma unroll
    for (int i = 1; i < 16; ++i) {
      if (kh[i] > bv) { bv = kh[i]; bi = i*256 + t; }  // increasing n: strict > keeps lowest
    }
    #pragma unroll
    for (int s = 1; s < 64; s <<= 1) {
      float ov = __shfl_xor(bv, s, 64);
      int   oi = __shfl_xor(bi, s, 64);
      if (ov > bv || (ov == bv && oi < bi)) { bv = ov; bi = oi; }
    }
    if (lane == 0) { selV[j*4+wave] = bv; selIdx[j*4+wave] = bi; }
    __syncthreads();
    bv = selV[j*4]; bi = selIdx[j*4];
    #pragma unroll
    for (int w = 1; w < 4; ++w) {
      float ov = selV[j*4+w]; int oi = selIdx[j*4+w];
      if (ov > bv || (ov == bv && oi < bi)) { bv = ov; bi = oi; }
    }
    id[j] = bi; rr[j] = (1.f - bv) + bv;
    if ((bi & 255) == t) kh[bi >> 8] = -1.f;   // exclude selected position
  }
  if (t == 0) {
    for (int a = 0; a < 3; ++a)
      for (int c2 = a+1; c2 < 4; ++c2)
        if (id[c2] < id[a]) { int ti=id[a]; id[a]=id[c2]; id[c2]=ti; float tr=rr[a]; rr[a]=rr[c2]; rr[c2]=tr; }
    int* iout = (int*)(ws + OFF_IDX);
    float* rout = ws + OFF_RV;
    for (int j = 0; j < 4; ++j) {
      iout[(sign*BB + b)*4 + j] = id[j];
      rout[(sign*BB + b)*4 + j] = rr[j];
    }
  }
}

// K10: assemble (b, 32, 256) output
__global__ __launch_bounds__(256) void k10_out(
    const float* __restrict__ keys, const float* __restrict__ query_pe,
    const float* __restrict__ point_pos, const float* __restrict__ point_neg,
    const float* __restrict__ pe_gauss,
    float* __restrict__ ws, float* __restrict__ out)
{
  int b = blockIdx.y, r = blockIdx.x, t = threadIdx.x;
  const float* G = ws + OFF_G;
  float val;
  if (r < 8) {
    val = (r == 1) ? (ws+OFF_REFT)[b*CC + t]
                   : (ws+OFF_QATT)[((size_t)b*NQn + r)*CC + t];
  } else if (r < 16) {
    int j = r - 8; int sign = j >> 2; int jj = j & 3;
    int idx = ((const int*)(ws+OFF_IDX))[(sign*BB + b)*4 + jj];
    float rvv = (ws+OFF_RV)[(sign*BB + b)*4 + jj];
    float kv = keys[((size_t)b*NK + idx)*CC + t];
    float gv = G[((size_t)b*NK + idx)*CC + t];
    val = (kv + gv) * rvv;
  } else if (r < 24) {
    val = query_pe[((size_t)b*NQn + (r-16))*CC + t];
  } else {
    int j = r - 24; int sign = j >> 2; int jj = j & 3;
    int idx = ((const int*)(ws+OFF_IDX))[(sign*BB + b)*4 + jj];
    float rvv = (ws+OFF_RV)[(sign*BB + b)*4 + jj];
    const float* point = sign ? point_neg : point_pos;
    int h = idx >> 6, w = idx & 63;
    float x = (w + 0.5f)/64.f, y = (h + 0.5f)/64.f;
    int jf = (t < 128) ? t : (t - 128);
    float proj = ((2.f*x - 1.f)*pe_gauss[jf] + (2.f*y - 1.f)*pe_gauss[128 + jf]) * 6.28318530717958647692f;
    float sv = (t < 128) ? sinf(proj) : cosf(proj);
    val = sv*rvv + point[t];
  }
  out[((size_t)b*32 + r)*CC + t] = val;
}

extern "C" void kernel_launch(void* const* d_in, const int* in_sizes, int n_in,
                              void* d_out, int out_size, void* d_ws, size_t ws_size,
                              hipStream_t stream)
{
  const float* queries   = (const float*)d_in[0];
  const float* keys      = (const float*)d_in[1];
  const float* query_pe  = (const float*)d_in[2];
  const float* key_pe    = (const float*)d_in[3];
  const float* guiding   = (const float*)d_in[4];
  const float* gumbel_p  = (const float*)d_in[5];
  const float* gumbel_n  = (const float*)d_in[6];
  const float* s_unc     = (const float*)d_in[7];
  const float* s_ref     = (const float*)d_in[8];
  const float* Wq  = (const float*)d_in[9];   const float* bq  = (const float*)d_in[10];
  const float* Wk  = (const float*)d_in[11];  const float* bk  = (const float*)d_in[12];
  const float* Wv  = (const float*)d_in[13];  const float* bv  = (const float*)d_in[14];
  const float* Wo  = (const float*)d_in[15];  const float* bo  = (const float*)d_in[16];
  const float* uW1 = (const float*)d_in[17];  const float* ub1 = (const float*)d_in[18];
  const float* uW2 = (const float*)d_in[19];  const float* ub2 = (const float*)d_in[20];
  const float* uW3 = (const float*)d_in[21];  const float* ub3 = (const float*)d_in[22];
  const float* rW1 = (const float*)d_in[23];  const float* rb1 = (const float*)d_in[24];
  const float* rW2 = (const float*)d_in[25];  const float* rb2 = (const float*)d_in[26];
  const float* rW3 = (const float*)d_in[27];  const float* rb3 = (const float*)d_in[28];
  const float* pe_gauss  = (const float*)d_in[29];
  const float* point_pos = (const float*)d_in[30];
  const float* point_neg = (const float*)d_in[31];
  float* ws = (float*)d_ws;
  float* out = (float*)d_out;

  k1_qside  <<<dim3(BB*NQn),  256, 0, stream>>>(queries, query_pe, Wq, bq, Wk, bk, ws);
  k2_scores <<<dim3(64, BB),  256, 0, stream>>>(keys, key_pe, guiding, ws);
  k3a_stats <<<dim3(16, BB),  256, 0, stream>>>(ws);
  k3b_combine<<<dim3(BB),      64, 0, stream>>>(ws);
  k4_av     <<<dim3(16, BB),  512, 0, stream>>>(ws);
  k56_attout<<<dim3(BB*NQn),  256, 0, stream>>>(Wv, bv, Wo, bo, ws);
  k7_mlps   <<<dim3(BB),      256, 0, stream>>>(s_unc, s_ref, uW1, ub1, uW2, ub2, uW3, ub3,
                                                rW1, rb1, rW2, rb2, rW3, rb3, ws);
  k8_masks  <<<dim3(64, BB),  256, 0, stream>>>(ws);
  k9_gumbel <<<dim3(2, BB),   256, 0, stream>>>(gumbel_p, gumbel_n, ws);
  k10_out   <<<dim3(32, BB),  256, 0, stream>>>(keys, query_pe, point_pos, point_neg,
                                                pe_gauss, ws, out);
}